// Round 1
// baseline (1636.120 us; speedup 1.0000x reference)
//
#include <hip/hip_runtime.h>

#define NN 20000
#define TT 2
#define HH 128
#define LL 4
#define EE 320000
#define FF 514
#define CN 3
#define CG 2
#define EPS_MSG 1e-7f

// ---------------- wave helpers ----------------
__device__ inline float wave_sum(float v) {
#pragma unroll
  for (int off = 32; off; off >>= 1) v += __shfl_xor(v, off);
  return v;
}

// ---------------- generic f32 GEMM: C = A[M,K]@B[K,N] + bias (+D) (+relu) ----
template <bool RELU, bool ADD>
__global__ __launch_bounds__(256) void gemm_f32(
    const float* __restrict__ A, const float* __restrict__ B,
    const float* __restrict__ bias, const float* __restrict__ D,
    float* __restrict__ C, int M, int N, int K) {
  __shared__ float As[16][65];
  __shared__ float Bs[16][65];
  int tid = threadIdx.x;
  int tx = tid & 15, ty = tid >> 4;
  int bm = blockIdx.y * 64, bn = blockIdx.x * 64;
  float acc[4][4] = {};
  for (int k0 = 0; k0 < K; k0 += 16) {
#pragma unroll
    for (int r = 0; r < 4; ++r) {
      int idx = tid + r * 256;
      int m = idx >> 4, k = idx & 15;
      int gm = bm + m, gk = k0 + k;
      float v = 0.f;
      if (gm < M && gk < K) v = A[(size_t)gm * K + gk];
      As[k][m] = v;
    }
#pragma unroll
    for (int r = 0; r < 4; ++r) {
      int idx = tid + r * 256;
      int k = idx >> 6, n = idx & 63;
      int gk = k0 + k, gn = bn + n;
      float v = 0.f;
      if (gk < K && gn < N) v = B[(size_t)gk * N + gn];
      Bs[k][n] = v;
    }
    __syncthreads();
#pragma unroll
    for (int k = 0; k < 16; ++k) {
      float a[4], b[4];
#pragma unroll
      for (int i = 0; i < 4; ++i) a[i] = As[k][ty * 4 + i];
#pragma unroll
      for (int j = 0; j < 4; ++j) b[j] = Bs[k][tx * 4 + j];
#pragma unroll
      for (int i = 0; i < 4; ++i)
#pragma unroll
        for (int j = 0; j < 4; ++j) acc[i][j] += a[i] * b[j];
    }
    __syncthreads();
  }
#pragma unroll
  for (int i = 0; i < 4; ++i) {
    int gm = bm + ty * 4 + i;
    if (gm >= M) continue;
#pragma unroll
    for (int j = 0; j < 4; ++j) {
      int gn = bn + tx * 4 + j;
      if (gn >= N) continue;
      float c = acc[i][j] + bias[gn];
      if (ADD) c += D[(size_t)gm * N + gn];
      if (RELU) c = fmaxf(c, 0.f);
      C[(size_t)gm * N + gn] = c;
    }
  }
}

// ---------------- row LayerNorm + ReLU (wave per row) ----------------
template <int W>
__global__ __launch_bounds__(256) void lnrelu_kernel(
    const float* __restrict__ X, const float* __restrict__ g,
    const float* __restrict__ b, float* __restrict__ Y, int rows, int ostride) {
  int wave = threadIdx.x >> 6, lane = threadIdx.x & 63;
  int n = blockIdx.x * 4 + wave;
  if (n >= rows) return;
  constexpr int C = W / 64;
  float v[C];
  const float* rowp = X + (size_t)n * W + lane * C;
  if constexpr (C == 2) {
    float2 t2 = *(const float2*)rowp;
    v[0] = t2.x; v[1] = t2.y;
  } else {
    float4 t4 = *(const float4*)rowp;
    v[0] = t4.x; v[1] = t4.y; v[2] = t4.z; v[3] = t4.w;
  }
  float s = 0.f, s2 = 0.f;
#pragma unroll
  for (int i = 0; i < C; ++i) { s += v[i]; s2 += v[i] * v[i]; }
  s = wave_sum(s);
  s2 = wave_sum(s2);
  float mu = s * (1.f / W);
  float var = fmaxf(s2 * (1.f / W) - mu * mu, 0.f);
  float r = rsqrtf(var + 1e-5f);
  float* op = Y + (size_t)n * ostride + lane * C;
#pragma unroll
  for (int i = 0; i < C; ++i) {
    float gv = g[lane * C + i], bv = b[lane * C + i];
    float y = (v[i] - mu) * r * gv + bv;
    op[i] = fmaxf(y, 0.f);
  }
}

// ---------------- CSR build ----------------
__global__ void count_kernel(const int* __restrict__ dst, int* __restrict__ deg, int E) {
  int i = blockIdx.x * blockDim.x + threadIdx.x;
  if (i < E) atomicAdd(&deg[dst[i]], 1);
}

__global__ __launch_bounds__(1024) void scan_kernel(
    const int* __restrict__ deg, int* __restrict__ rowptr,
    int* __restrict__ cursor, int n, int total) {
  __shared__ int sums[1024];
  int tid = threadIdx.x;
  int chunk = (n + 1023) / 1024;
  int begin = tid * chunk, end = min(begin + chunk, n);
  int s = 0;
  for (int i = begin; i < end; ++i) s += deg[i];
  sums[tid] = s;
  __syncthreads();
  for (int off = 1; off < 1024; off <<= 1) {
    int v = (tid >= off) ? sums[tid - off] : 0;
    __syncthreads();
    sums[tid] += v;
    __syncthreads();
  }
  int running = sums[tid] - s;  // exclusive prefix
  for (int i = begin; i < end; ++i) {
    rowptr[i] = running;
    cursor[i] = running;
    running += deg[i];
  }
  if (tid == 0) rowptr[n] = total;
}

__global__ void scatter_kernel(const int* __restrict__ src, const int* __restrict__ dst,
                               const float* __restrict__ ea, int* __restrict__ cursor,
                               int* __restrict__ esrc, float2* __restrict__ eattr, int E) {
  int i = blockIdx.x * blockDim.x + threadIdx.x;
  if (i >= E) return;
  int d = dst[i];
  int pos = atomicAdd(&cursor[d], 1);
  esrc[pos] = src[i];
  eattr[pos] = ((const float2*)ea)[i];
}

// ---------------- GENConv softmax aggregation + residual ----------------
// out[n,:] = sum_j msg_j * softmax_j(msg_j * t) + xin[n,:]
// msg = relu(x[src] + ea@Wee + bee) + EPS.  Computed without max-subtraction
// (exp args bounded; mathematically identical).
__global__ __launch_bounds__(256) void agg_kernel(
    const float* __restrict__ xin, const int* __restrict__ rowptr,
    const int* __restrict__ esrc, const float2* __restrict__ eattr,
    const float* __restrict__ Wee, const float* __restrict__ bee,
    const float* __restrict__ tptr, int layer, float* __restrict__ out, int nNodes) {
  int wave = threadIdx.x >> 6, lane = threadIdx.x & 63;
  int n = blockIdx.x * 4 + wave;
  if (n >= nNodes) return;
  float t = tptr[layer];
  int c0 = lane * 2;
  float w00 = Wee[c0], w01 = Wee[c0 + 1];
  float w10 = Wee[HH + c0], w11 = Wee[HH + c0 + 1];
  float be0 = bee[c0], be1 = bee[c0 + 1];
  float den0 = 0.f, den1 = 0.f, num0 = 0.f, num1 = 0.f;
  int e0 = rowptr[n], e1 = rowptr[n + 1];
  for (int e = e0; e < e1; ++e) {
    int s = esrc[e];
    float2 ea = eattr[e];
    float2 xs = *(const float2*)(xin + (size_t)s * HH + c0);
    float m0 = xs.x + ea.x * w00 + ea.y * w10 + be0;
    float m1 = xs.y + ea.x * w01 + ea.y * w11 + be1;
    m0 = fmaxf(m0, 0.f) + EPS_MSG;
    m1 = fmaxf(m1, 0.f) + EPS_MSG;
    float ex0 = __expf(m0 * t), ex1 = __expf(m1 * t);
    den0 += ex0; den1 += ex1;
    num0 += m0 * ex0; num1 += m1 * ex1;
  }
  float2 xr = *(const float2*)(xin + (size_t)n * HH + c0);
  float o0 = num0 / (den0 + 1e-16f) + xr.x;
  float o1 = num1 / (den1 + 1e-16f) + xr.y;
  *(float2*)(out + (size_t)n * HH + c0) = make_float2(o0, o1);
}

// ---------------- channel attention over T=2 (wave per node) ----------------
__global__ __launch_bounds__(256) void attn_kernel(
    const float* __restrict__ emb, const float* __restrict__ Wq,
    const float* __restrict__ Wk, const float* __restrict__ Wv,
    const float* __restrict__ gammap, float* __restrict__ out, int nNodes) {
  int wave = threadIdx.x >> 6, lane = threadIdx.x & 63;
  int n = blockIdx.x * 4 + wave;
  if (n >= nNodes) return;
  float gamma = *gammap;
  float wq00 = Wq[0], wq01 = Wq[1], wq10 = Wq[2], wq11 = Wq[3];
  float wk00 = Wk[0], wk01 = Wk[1], wk10 = Wk[2], wk11 = Wk[3];
  float wv00 = Wv[0], wv01 = Wv[1], wv10 = Wv[2], wv11 = Wv[3];
  int c0 = lane * 2;
  const float* base = emb + (size_t)n * (2 * HH);
  float2 x0 = *(const float2*)(base + c0);
  float2 x1 = *(const float2*)(base + HH + c0);
  float q0a = wq00 * x0.x + wq01 * x1.x, q0b = wq00 * x0.y + wq01 * x1.y;
  float q1a = wq10 * x0.x + wq11 * x1.x, q1b = wq10 * x0.y + wq11 * x1.y;
  float k0a = wk00 * x0.x + wk01 * x1.x, k0b = wk00 * x0.y + wk01 * x1.y;
  float k1a = wk10 * x0.x + wk11 * x1.x, k1b = wk10 * x0.y + wk11 * x1.y;
  float v0a = wv00 * x0.x + wv01 * x1.x, v0b = wv00 * x0.y + wv01 * x1.y;
  float v1a = wv10 * x0.x + wv11 * x1.x, v1b = wv10 * x0.y + wv11 * x1.y;
  float s00 = wave_sum(q0a * k0a + q0b * k0b);
  float s01 = wave_sum(q0a * k1a + q0b * k1b);
  float s10 = wave_sum(q1a * k0a + q1b * k0b);
  float s11 = wave_sum(q1a * k1a + q1b * k1b);
  float m0 = fmaxf(s00, s01);
  float e00 = __expf(s00 - m0), e01 = __expf(s01 - m0);
  float i0 = 1.f / (e00 + e01);
  float a00 = e00 * i0, a01 = e01 * i0;
  float m1 = fmaxf(s10, s11);
  float e10 = __expf(s10 - m1), e11 = __expf(s11 - m1);
  float i1 = 1.f / (e10 + e11);
  float a10 = e10 * i1, a11 = e11 * i1;
  float* op = out + (size_t)n * (2 * HH);
  op[c0] = gamma * (a00 * v0a + a01 * v1a) + x0.x;
  op[c0 + 1] = gamma * (a00 * v0b + a01 * v1b) + x0.y;
  op[HH + c0] = gamma * (a10 * v0a + a11 * v1a) + x1.x;
  op[HH + c0 + 1] = gamma * (a10 * v0b + a11 * v1b) + x1.y;
}

// ---------------- node head: logits3 + log_softmax (wave per node) ----------
__global__ __launch_bounds__(256) void node_head_kernel(
    const float* __restrict__ tmp, const float* __restrict__ Wn2,
    const float* __restrict__ bn2, float* __restrict__ outp, int nNodes) {
  int wave = threadIdx.x >> 6, lane = threadIdx.x & 63;
  int n = blockIdx.x * 4 + wave;
  if (n >= nNodes) return;
  const float* row = tmp + (size_t)n * 256;
  float4 xv = *(const float4*)(row + lane * 4);
  float xs[4] = {xv.x, xv.y, xv.z, xv.w};
  float p0 = 0.f, p1 = 0.f, p2 = 0.f;
#pragma unroll
  for (int i = 0; i < 4; ++i) {
    int c = lane * 4 + i;
    p0 += xs[i] * Wn2[c * 3 + 0];
    p1 += xs[i] * Wn2[c * 3 + 1];
    p2 += xs[i] * Wn2[c * 3 + 2];
  }
  p0 = wave_sum(p0); p1 = wave_sum(p1); p2 = wave_sum(p2);
  if (lane == 0) {
    float l0 = p0 + bn2[0], l1 = p1 + bn2[1], l2 = p2 + bn2[2];
    float m = fmaxf(l0, fmaxf(l1, l2));
    float lse = m + logf(__expf(l0 - m) + __expf(l1 - m) + __expf(l2 - m));
    outp[(size_t)n * 3 + 0] = l0 - lse;
    outp[(size_t)n * 3 + 1] = l1 - lse;
    outp[(size_t)n * 3 + 2] = l2 - lse;
  }
}

// ---------------- mean pool ----------------
__global__ __launch_bounds__(256) void pool_kernel(const float* __restrict__ gbuf,
                                                   float* __restrict__ gp_sum, int nNodes) {
  int c = threadIdx.x;
  float s = 0.f;
  for (int r = blockIdx.x; r < nNodes; r += gridDim.x) s += gbuf[(size_t)r * 256 + c];
  atomicAdd(&gp_sum[c], s);
}

// ---------------- graph head (single block) ----------------
__global__ __launch_bounds__(256) void graph_head_kernel(
    const float* __restrict__ gp_sum, const float* __restrict__ Wg1,
    const float* __restrict__ bg1, const float* __restrict__ Wg2,
    const float* __restrict__ bg2, float* __restrict__ outp, float invN) {
  __shared__ float gp[256];
  __shared__ float h1[256];
  __shared__ float lg[2];
  int tid = threadIdx.x;
  gp[tid] = gp_sum[tid] * invN;
  __syncthreads();
  float acc = bg1[tid];
  for (int k = 0; k < 256; ++k) acc += gp[k] * Wg1[k * 256 + tid];
  h1[tid] = fmaxf(acc, 0.f);
  __syncthreads();
  if (tid < 2) {
    float l = bg2[tid];
    for (int c = 0; c < 256; ++c) l += h1[c] * Wg2[c * 2 + tid];
    lg[tid] = l;
  }
  __syncthreads();
  if (tid == 0) {
    float m = fmaxf(lg[0], lg[1]);
    float lse = m + logf(__expf(lg[0] - m) + __expf(lg[1] - m));
    outp[0] = lg[0] - lse;
    outp[1] = lg[1] - lse;
  }
}

// ---------------- launch ----------------
extern "C" void kernel_launch(void* const* d_in, const int* in_sizes, int n_in,
                              void* d_out, int out_size, void* d_ws, size_t ws_size,
                              hipStream_t stream) {
  (void)in_sizes; (void)n_in; (void)out_size; (void)ws_size;
  const float* node_feature = (const float*)d_in[0];
  const int* edge_index = (const int*)d_in[1];
  const float* edge_attr = (const float*)d_in[2];
  const float* Wne = (const float*)d_in[3];
  const float* bne = (const float*)d_in[4];
  const float* Wee = (const float*)d_in[5];
  const float* bee = (const float*)d_in[6];
  const float* W1 = (const float*)d_in[7];
  const float* b1 = (const float*)d_in[8];
  const float* g1 = (const float*)d_in[9];
  const float* be1 = (const float*)d_in[10];
  const float* W2 = (const float*)d_in[11];
  const float* b2 = (const float*)d_in[12];
  const float* dg = (const float*)d_in[13];
  const float* db = (const float*)d_in[14];
  const float* tpar = (const float*)d_in[15];
  const float* Wq_n = (const float*)d_in[16];
  const float* Wk_n = (const float*)d_in[17];
  const float* Wv_n = (const float*)d_in[18];
  const float* gamma_n = (const float*)d_in[19];
  const float* Wn1 = (const float*)d_in[20];
  const float* bn1 = (const float*)d_in[21];
  const float* Wn2 = (const float*)d_in[22];
  const float* bn2 = (const float*)d_in[23];
  const float* Wq_g = (const float*)d_in[24];
  const float* Wk_g = (const float*)d_in[25];
  const float* Wv_g = (const float*)d_in[26];
  const float* gamma_g = (const float*)d_in[27];
  const float* Wg1 = (const float*)d_in[28];
  const float* bg1 = (const float*)d_in[29];
  const float* Wg2 = (const float*)d_in[30];
  const float* bg2 = (const float*)d_in[31];
  float* out = (float*)d_out;

  // workspace carve-out (all region sizes even in 4B units; float2 stays 8B aligned)
  float* p = (float*)d_ws;
  float* x_enc = p;  p += (size_t)NN * HH;
  float* xbuf = p;   p += (size_t)NN * HH;
  float* hbuf = p;   p += (size_t)NN * HH;
  float* aggout = p; p += (size_t)NN * HH;
  float* tmp256 = p; p += (size_t)NN * 2 * HH;   // also node-attn output
  float* emb = p;    p += (size_t)NN * 2 * HH;
  float* buf2 = p;   p += (size_t)NN * 2 * HH;   // node-head tmp, then graph-attn out
  float* gp_sum = p; p += 256;
  int* deg = (int*)p;    p += NN;
  int* cursor = (int*)p; p += NN;
  int* rowptr = (int*)p; p += NN + 2;            // +2 keeps parity even
  int* esrc = (int*)p;   p += EE;
  float2* eattr = (float2*)p;

  const int rows4 = (NN + 3) / 4;                 // 5000 blocks, wave-per-row kernels
  const dim3 gEnc((HH + 63) / 64, (NN + 63) / 64);
  const dim3 gG1((2 * HH + 63) / 64, (NN + 63) / 64);
  const dim3 gG2((HH + 63) / 64, (NN + 63) / 64);
  const dim3 gHead((256 + 63) / 64, (NN + 63) / 64);

  // 1. node encoder (ti-independent — computed once)
  gemm_f32<false, false><<<gEnc, 256, 0, stream>>>(node_feature, Wne, bne, nullptr,
                                                   x_enc, NN, HH, FF);

  for (int ti = 0; ti < TT; ++ti) {
    const int* src = edge_index + (size_t)ti * 2 * EE;
    const int* dst = src + EE;
    const float* ea = edge_attr + (size_t)ti * EE * 2;

    hipMemsetAsync(deg, 0, NN * sizeof(int), stream);
    count_kernel<<<(EE + 255) / 256, 256, 0, stream>>>(dst, deg, EE);
    scan_kernel<<<1, 1024, 0, stream>>>(deg, rowptr, cursor, NN, EE);
    scatter_kernel<<<(EE + 255) / 256, 256, 0, stream>>>(src, dst, ea, cursor, esrc,
                                                         eattr, EE);

    for (int l = 0; l < LL; ++l) {
      const float* gin;
      if (l == 0) {
        gin = x_enc;
      } else {
        lnrelu_kernel<128><<<rows4, 256, 0, stream>>>(xbuf, dg + l * HH, db + l * HH,
                                                      hbuf, NN, HH);
        gin = hbuf;
      }
      agg_kernel<<<rows4, 256, 0, stream>>>(gin, rowptr, esrc, eattr, Wee, bee, tpar,
                                            l, aggout, NN);
      gemm_f32<false, false><<<gG1, 256, 0, stream>>>(
          aggout, W1 + (size_t)l * HH * 2 * HH, b1 + l * 2 * HH, nullptr, tmp256, NN,
          2 * HH, HH);
      lnrelu_kernel<256><<<rows4, 256, 0, stream>>>(tmp256, g1 + l * 2 * HH,
                                                    be1 + l * 2 * HH, tmp256, NN,
                                                    2 * HH);
      if (l == 0)
        gemm_f32<false, false><<<gG2, 256, 0, stream>>>(
            tmp256, W2 + (size_t)l * 2 * HH * HH, b2 + l * HH, nullptr, xbuf, NN, HH,
            2 * HH);
      else
        gemm_f32<false, true><<<gG2, 256, 0, stream>>>(
            tmp256, W2 + (size_t)l * 2 * HH * HH, b2 + l * HH, xbuf, xbuf, NN, HH,
            2 * HH);
    }
    // final relu(LN(x; dg[0], db[0])) -> emb[:, ti, :]
    lnrelu_kernel<128><<<rows4, 256, 0, stream>>>(xbuf, dg, db, emb + ti * HH, NN,
                                                  2 * HH);
  }

  // node branch
  attn_kernel<<<rows4, 256, 0, stream>>>(emb, Wq_n, Wk_n, Wv_n, gamma_n, tmp256, NN);
  gemm_f32<true, false><<<gHead, 256, 0, stream>>>(tmp256, Wn1, bn1, nullptr, buf2, NN,
                                                   256, 256);
  node_head_kernel<<<rows4, 256, 0, stream>>>(buf2, Wn2, bn2, out, NN);

  // graph branch
  attn_kernel<<<rows4, 256, 0, stream>>>(emb, Wq_g, Wk_g, Wv_g, gamma_g, buf2, NN);
  hipMemsetAsync(gp_sum, 0, 256 * sizeof(float), stream);
  pool_kernel<<<128, 256, 0, stream>>>(buf2, gp_sum, NN);
  graph_head_kernel<<<1, 256, 0, stream>>>(gp_sum, Wg1, bg1, Wg2, bg2,
                                           out + (size_t)NN * CN, 1.0f / NN);
}

// Round 2
// 1027.504 us; speedup vs baseline: 1.5923x; 1.5923x over previous
//
#include <hip/hip_runtime.h>

#define NN 20000
#define TT 2
#define HH 128
#define LL 4
#define EE 320000
#define FF 514
#define CN 3
#define CG 2
#define EPS_MSG 1e-7f
#define MP 20096  // M padded to multiple of 128

typedef __bf16 bf16x8 __attribute__((ext_vector_type(8)));
typedef float f32x4 __attribute__((ext_vector_type(4)));

// ---------------- wave helpers ----------------
__device__ inline float wave_sum(float v) {
#pragma unroll
  for (int off = 32; off; off >>= 1) v += __shfl_xor(v, off);
  return v;
}

__device__ __forceinline__ void gload_lds16(const void* g, void* l) {
  __builtin_amdgcn_global_load_lds(
      (const __attribute__((address_space(1))) unsigned int*)g,
      (__attribute__((address_space(3))) unsigned int*)l, 16, 0, 0);
}

// ---------------- bf16 MFMA GEMM: C = A[M,K]@BT[N,K]^T + bias (+D)(+relu) ----
// A: bf16 [>=M rows padded to 128][K], K%32==0. BT: bf16 [N][K], N%128==0.
// C: f32 [M][N]. 128x128 tile, 4 waves, each wave 64x64 via 4x4 frags 16x16x32.
template <bool RELU, bool ADD>
__global__ __launch_bounds__(256) void gemm_mfma(
    const __bf16* __restrict__ A, const __bf16* __restrict__ BT,
    const float* __restrict__ bias, const float* __restrict__ D,
    float* __restrict__ C, int M, int N, int K) {
  __shared__ __bf16 As[128][32];
  __shared__ __bf16 Bs[128][32];
  const int tid = threadIdx.x;
  const int lane = tid & 63, w = tid >> 6;
  const int bm = blockIdx.y * 128, bn = blockIdx.x * 128;
  const int wr = (w >> 1) * 64, wc = (w & 1) * 64;
  const int fr = lane & 15, fq = lane >> 4;
  // staging: wave w stages rows [w*16, w*16+16) (+64 on 2nd rep); lane -> 16B chunk
  const int srow = w * 16 + (lane >> 2);
  const int sch = (lane & 3) * 8;
  f32x4 acc[4][4] = {};
  const __bf16* Ab = A + (size_t)bm * K;
  const __bf16* Bb = BT + (size_t)bn * K;
  for (int k0 = 0; k0 < K; k0 += 32) {
#pragma unroll
    for (int r = 0; r < 2; ++r) {
      gload_lds16(Ab + (size_t)(srow + r * 64) * K + k0 + sch, &As[srow + r * 64][sch]);
      gload_lds16(Bb + (size_t)(srow + r * 64) * K + k0 + sch, &Bs[srow + r * 64][sch]);
    }
    __syncthreads();
    bf16x8 af[4], bq[4];
#pragma unroll
    for (int m = 0; m < 4; ++m)
      af[m] = *(const bf16x8*)&As[wr + m * 16 + fr][fq * 8];
#pragma unroll
    for (int n = 0; n < 4; ++n)
      bq[n] = *(const bf16x8*)&Bs[wc + n * 16 + fr][fq * 8];
#pragma unroll
    for (int m = 0; m < 4; ++m)
#pragma unroll
      for (int n = 0; n < 4; ++n)
        acc[m][n] =
            __builtin_amdgcn_mfma_f32_16x16x32_bf16(af[m], bq[n], acc[m][n], 0, 0, 0);
    __syncthreads();
  }
#pragma unroll
  for (int m = 0; m < 4; ++m) {
#pragma unroll
    for (int n = 0; n < 4; ++n) {
#pragma unroll
      for (int j = 0; j < 4; ++j) {
        int gm = bm + wr + m * 16 + fq * 4 + j;
        int gn = bn + wc + n * 16 + fr;
        if (gm < M) {
          float c = acc[m][n][j] + bias[gn];
          if (ADD) c += D[(size_t)gm * N + gn];
          if (RELU) c = fmaxf(c, 0.f);
          C[(size_t)gm * N + gn] = c;
        }
      }
    }
  }
}

// ---------------- conversions ----------------
__global__ void nf_convert_kernel(const float* __restrict__ src, __bf16* __restrict__ dst) {
  int idx = blockIdx.x * 256 + threadIdx.x;
  if (idx >= NN * 576) return;
  int row = idx / 576, col = idx - row * 576;
  float v = (col < FF) ? src[(size_t)row * FF + col] : 0.f;
  dst[idx] = (__bf16)v;
}

struct WtDesc { const float* src; __bf16* dst; int K, N, Kpad; };
struct WtDescs { WtDesc d[10]; };

__global__ void wt_convert_kernel(WtDescs descs) {
  WtDesc de = descs.d[blockIdx.y];
  int idx = blockIdx.x * 256 + threadIdx.x;
  if (idx >= de.N * de.Kpad) return;
  int n = idx / de.Kpad, k = idx - n * de.Kpad;
  float v = (k < de.K) ? de.src[(size_t)k * de.N + n] : 0.f;
  de.dst[idx] = (__bf16)v;
}

// ---------------- row LayerNorm + ReLU (wave per row) ----------------
template <int W, typename OT>
__global__ __launch_bounds__(256) void lnrelu_kernel(
    const float* __restrict__ X, const float* __restrict__ g,
    const float* __restrict__ b, OT* __restrict__ Y, int rows, int ostride) {
  int wave = threadIdx.x >> 6, lane = threadIdx.x & 63;
  int n = blockIdx.x * 4 + wave;
  if (n >= rows) return;
  constexpr int C = W / 64;
  float v[C];
  const float* rowp = X + (size_t)n * W + lane * C;
  if constexpr (C == 2) {
    float2 t2 = *(const float2*)rowp;
    v[0] = t2.x; v[1] = t2.y;
  } else {
    float4 t4 = *(const float4*)rowp;
    v[0] = t4.x; v[1] = t4.y; v[2] = t4.z; v[3] = t4.w;
  }
  float s = 0.f, s2 = 0.f;
#pragma unroll
  for (int i = 0; i < C; ++i) { s += v[i]; s2 += v[i] * v[i]; }
  s = wave_sum(s);
  s2 = wave_sum(s2);
  float mu = s * (1.f / W);
  float var = fmaxf(s2 * (1.f / W) - mu * mu, 0.f);
  float r = rsqrtf(var + 1e-5f);
  OT* op = Y + (size_t)n * ostride + lane * C;
#pragma unroll
  for (int i = 0; i < C; ++i) {
    float gv = g[lane * C + i], bv = b[lane * C + i];
    float y = (v[i] - mu) * r * gv + bv;
    op[i] = (OT)fmaxf(y, 0.f);
  }
}

// ---------------- CSR build ----------------
__global__ void count_kernel(const int* __restrict__ dst, int* __restrict__ deg, int E) {
  int i = blockIdx.x * blockDim.x + threadIdx.x;
  if (i < E) atomicAdd(&deg[dst[i]], 1);
}

__global__ __launch_bounds__(1024) void scan_kernel(
    const int* __restrict__ deg, int* __restrict__ rowptr,
    int* __restrict__ cursor, int n, int total) {
  __shared__ int sums[1024];
  int tid = threadIdx.x;
  int chunk = (n + 1023) / 1024;
  int begin = tid * chunk, end = min(begin + chunk, n);
  int s = 0;
  for (int i = begin; i < end; ++i) s += deg[i];
  sums[tid] = s;
  __syncthreads();
  for (int off = 1; off < 1024; off <<= 1) {
    int v = (tid >= off) ? sums[tid - off] : 0;
    __syncthreads();
    sums[tid] += v;
    __syncthreads();
  }
  int running = sums[tid] - s;  // exclusive prefix
  for (int i = begin; i < end; ++i) {
    rowptr[i] = running;
    cursor[i] = running;
    running += deg[i];
  }
  if (tid == 0) rowptr[n] = total;
}

__global__ void scatter_kernel(const int* __restrict__ src, const int* __restrict__ dst,
                               const float* __restrict__ ea, int* __restrict__ cursor,
                               int* __restrict__ esrc, float2* __restrict__ eattr, int E) {
  int i = blockIdx.x * blockDim.x + threadIdx.x;
  if (i >= E) return;
  int d = dst[i];
  int pos = atomicAdd(&cursor[d], 1);
  esrc[pos] = src[i];
  eattr[pos] = ((const float2*)ea)[i];
}

// ---------------- GENConv softmax aggregation + residual (bf16 out) --------
__global__ __launch_bounds__(256) void agg_kernel(
    const float* __restrict__ xin, const int* __restrict__ rowptr,
    const int* __restrict__ esrc, const float2* __restrict__ eattr,
    const float* __restrict__ Wee, const float* __restrict__ bee,
    const float* __restrict__ tptr, int layer, __bf16* __restrict__ out, int nNodes) {
  int wave = threadIdx.x >> 6, lane = threadIdx.x & 63;
  int n = blockIdx.x * 4 + wave;
  if (n >= nNodes) return;
  float t = tptr[layer];
  int c0 = lane * 2;
  float w00 = Wee[c0], w01 = Wee[c0 + 1];
  float w10 = Wee[HH + c0], w11 = Wee[HH + c0 + 1];
  float be0 = bee[c0], be1 = bee[c0 + 1];
  float den0 = 0.f, den1 = 0.f, num0 = 0.f, num1 = 0.f;
  int e0 = rowptr[n], e1 = rowptr[n + 1];
  for (int e = e0; e < e1; ++e) {
    int s = esrc[e];
    float2 ea = eattr[e];
    float2 xs = *(const float2*)(xin + (size_t)s * HH + c0);
    float m0 = xs.x + ea.x * w00 + ea.y * w10 + be0;
    float m1 = xs.y + ea.x * w01 + ea.y * w11 + be1;
    m0 = fmaxf(m0, 0.f) + EPS_MSG;
    m1 = fmaxf(m1, 0.f) + EPS_MSG;
    float ex0 = __expf(m0 * t), ex1 = __expf(m1 * t);
    den0 += ex0; den1 += ex1;
    num0 += m0 * ex0; num1 += m1 * ex1;
  }
  float2 xr = *(const float2*)(xin + (size_t)n * HH + c0);
  float o0 = num0 / (den0 + 1e-16f) + xr.x;
  float o1 = num1 / (den1 + 1e-16f) + xr.y;
  out[(size_t)n * HH + c0] = (__bf16)o0;
  out[(size_t)n * HH + c0 + 1] = (__bf16)o1;
}

// ---------------- channel attention over T=2 (wave per node) ----------------
template <typename OT>
__global__ __launch_bounds__(256) void attn_kernel(
    const float* __restrict__ emb, const float* __restrict__ Wq,
    const float* __restrict__ Wk, const float* __restrict__ Wv,
    const float* __restrict__ gammap, OT* __restrict__ out, int nNodes) {
  int wave = threadIdx.x >> 6, lane = threadIdx.x & 63;
  int n = blockIdx.x * 4 + wave;
  if (n >= nNodes) return;
  float gamma = *gammap;
  float wq00 = Wq[0], wq01 = Wq[1], wq10 = Wq[2], wq11 = Wq[3];
  float wk00 = Wk[0], wk01 = Wk[1], wk10 = Wk[2], wk11 = Wk[3];
  float wv00 = Wv[0], wv01 = Wv[1], wv10 = Wv[2], wv11 = Wv[3];
  int c0 = lane * 2;
  const float* base = emb + (size_t)n * (2 * HH);
  float2 x0 = *(const float2*)(base + c0);
  float2 x1 = *(const float2*)(base + HH + c0);
  float q0a = wq00 * x0.x + wq01 * x1.x, q0b = wq00 * x0.y + wq01 * x1.y;
  float q1a = wq10 * x0.x + wq11 * x1.x, q1b = wq10 * x0.y + wq11 * x1.y;
  float k0a = wk00 * x0.x + wk01 * x1.x, k0b = wk00 * x0.y + wk01 * x1.y;
  float k1a = wk10 * x0.x + wk11 * x1.x, k1b = wk10 * x0.y + wk11 * x1.y;
  float v0a = wv00 * x0.x + wv01 * x1.x, v0b = wv00 * x0.y + wv01 * x1.y;
  float v1a = wv10 * x0.x + wv11 * x1.x, v1b = wv10 * x0.y + wv11 * x1.y;
  float s00 = wave_sum(q0a * k0a + q0b * k0b);
  float s01 = wave_sum(q0a * k1a + q0b * k1b);
  float s10 = wave_sum(q1a * k0a + q1b * k0b);
  float s11 = wave_sum(q1a * k1a + q1b * k1b);
  float m0 = fmaxf(s00, s01);
  float e00 = __expf(s00 - m0), e01 = __expf(s01 - m0);
  float i0 = 1.f / (e00 + e01);
  float a00 = e00 * i0, a01 = e01 * i0;
  float m1 = fmaxf(s10, s11);
  float e10 = __expf(s10 - m1), e11 = __expf(s11 - m1);
  float i1 = 1.f / (e10 + e11);
  float a10 = e10 * i1, a11 = e11 * i1;
  OT* op = out + (size_t)n * (2 * HH);
  op[c0] = (OT)(gamma * (a00 * v0a + a01 * v1a) + x0.x);
  op[c0 + 1] = (OT)(gamma * (a00 * v0b + a01 * v1b) + x0.y);
  op[HH + c0] = (OT)(gamma * (a10 * v0a + a11 * v1a) + x1.x);
  op[HH + c0 + 1] = (OT)(gamma * (a10 * v0b + a11 * v1b) + x1.y);
}

// ---------------- node head: logits3 + log_softmax (wave per node) ----------
__global__ __launch_bounds__(256) void node_head_kernel(
    const float* __restrict__ tmp, const float* __restrict__ Wn2,
    const float* __restrict__ bn2, float* __restrict__ outp, int nNodes) {
  int wave = threadIdx.x >> 6, lane = threadIdx.x & 63;
  int n = blockIdx.x * 4 + wave;
  if (n >= nNodes) return;
  const float* row = tmp + (size_t)n * 256;
  float4 xv = *(const float4*)(row + lane * 4);
  float xs[4] = {xv.x, xv.y, xv.z, xv.w};
  float p0 = 0.f, p1 = 0.f, p2 = 0.f;
#pragma unroll
  for (int i = 0; i < 4; ++i) {
    int c = lane * 4 + i;
    p0 += xs[i] * Wn2[c * 3 + 0];
    p1 += xs[i] * Wn2[c * 3 + 1];
    p2 += xs[i] * Wn2[c * 3 + 2];
  }
  p0 = wave_sum(p0); p1 = wave_sum(p1); p2 = wave_sum(p2);
  if (lane == 0) {
    float l0 = p0 + bn2[0], l1 = p1 + bn2[1], l2 = p2 + bn2[2];
    float m = fmaxf(l0, fmaxf(l1, l2));
    float lse = m + logf(__expf(l0 - m) + __expf(l1 - m) + __expf(l2 - m));
    outp[(size_t)n * 3 + 0] = l0 - lse;
    outp[(size_t)n * 3 + 1] = l1 - lse;
    outp[(size_t)n * 3 + 2] = l2 - lse;
  }
}

// ---------------- mean pool ----------------
__global__ __launch_bounds__(256) void pool_kernel(const float* __restrict__ gbuf,
                                                   float* __restrict__ gp_sum, int nNodes) {
  int c = threadIdx.x;
  float s = 0.f;
  for (int r = blockIdx.x; r < nNodes; r += gridDim.x) s += gbuf[(size_t)r * 256 + c];
  atomicAdd(&gp_sum[c], s);
}

// ---------------- graph head (single block) ----------------
__global__ __launch_bounds__(256) void graph_head_kernel(
    const float* __restrict__ gp_sum, const float* __restrict__ Wg1,
    const float* __restrict__ bg1, const float* __restrict__ Wg2,
    const float* __restrict__ bg2, float* __restrict__ outp, float invN) {
  __shared__ float gp[256];
  __shared__ float h1[256];
  __shared__ float lg[2];
  int tid = threadIdx.x;
  gp[tid] = gp_sum[tid] * invN;
  __syncthreads();
  float acc = bg1[tid];
  for (int k = 0; k < 256; ++k) acc += gp[k] * Wg1[k * 256 + tid];
  h1[tid] = fmaxf(acc, 0.f);
  __syncthreads();
  if (tid < 2) {
    float l = bg2[tid];
    for (int c = 0; c < 256; ++c) l += h1[c] * Wg2[c * 2 + tid];
    lg[tid] = l;
  }
  __syncthreads();
  if (tid == 0) {
    float m = fmaxf(lg[0], lg[1]);
    float lse = m + logf(__expf(lg[0] - m) + __expf(lg[1] - m));
    outp[0] = lg[0] - lse;
    outp[1] = lg[1] - lse;
  }
}

// ---------------- launch ----------------
extern "C" void kernel_launch(void* const* d_in, const int* in_sizes, int n_in,
                              void* d_out, int out_size, void* d_ws, size_t ws_size,
                              hipStream_t stream) {
  (void)in_sizes; (void)n_in; (void)out_size; (void)ws_size;
  const float* node_feature = (const float*)d_in[0];
  const int* edge_index = (const int*)d_in[1];
  const float* edge_attr = (const float*)d_in[2];
  const float* Wne = (const float*)d_in[3];
  const float* bne = (const float*)d_in[4];
  const float* Wee = (const float*)d_in[5];
  const float* bee = (const float*)d_in[6];
  const float* W1 = (const float*)d_in[7];
  const float* b1 = (const float*)d_in[8];
  const float* g1 = (const float*)d_in[9];
  const float* be1 = (const float*)d_in[10];
  const float* W2 = (const float*)d_in[11];
  const float* b2 = (const float*)d_in[12];
  const float* dg = (const float*)d_in[13];
  const float* db = (const float*)d_in[14];
  const float* tpar = (const float*)d_in[15];
  const float* Wq_n = (const float*)d_in[16];
  const float* Wk_n = (const float*)d_in[17];
  const float* Wv_n = (const float*)d_in[18];
  const float* gamma_n = (const float*)d_in[19];
  const float* Wn1 = (const float*)d_in[20];
  const float* bn1 = (const float*)d_in[21];
  const float* Wn2 = (const float*)d_in[22];
  const float* bn2 = (const float*)d_in[23];
  const float* Wq_g = (const float*)d_in[24];
  const float* Wk_g = (const float*)d_in[25];
  const float* Wv_g = (const float*)d_in[26];
  const float* gamma_g = (const float*)d_in[27];
  const float* Wg1 = (const float*)d_in[28];
  const float* bg1 = (const float*)d_in[29];
  const float* Wg2 = (const float*)d_in[30];
  const float* bg2 = (const float*)d_in[31];
  float* out = (float*)d_out;

  // ---- workspace carve-out (256B-aligned regions) ----
  char* pc = (char*)d_ws;
  auto alloc = [&](size_t bytes) {
    char* r = pc;
    pc += (bytes + 255) & ~(size_t)255;
    return r;
  };
  float* x_enc = (float*)alloc((size_t)NN * HH * 4);
  float* xbuf = (float*)alloc((size_t)NN * HH * 4);
  float* hbuf = (float*)alloc((size_t)NN * HH * 4);
  float* tmp256 = (float*)alloc((size_t)NN * 2 * HH * 4);
  float* buf2 = tmp256;  // alias: head tmp / graph-attn out (disjoint in time)
  float* emb = (float*)alloc((size_t)NN * 2 * HH * 4);
  __bf16* aggout_b = (__bf16*)alloc((size_t)MP * HH * 2);
  __bf16* t256_b = (__bf16*)alloc((size_t)MP * 2 * HH * 2);
  __bf16* attnb = t256_b;  // alias: node-attn bf16 out (after last lin2)
  // nf_b aliases emb (+ spills into aggout_b region): used only before ti-loop
  __bf16* nf_b = (__bf16*)emb;  // needs 20096*576*2 = 23.2MB <= emb+aggout = 25.6MB
  __bf16* wt_ne = (__bf16*)alloc((size_t)128 * 576 * 2);
  __bf16* wt1 = (__bf16*)alloc((size_t)4 * 256 * 128 * 2);
  __bf16* wt2 = (__bf16*)alloc((size_t)4 * 128 * 256 * 2);
  __bf16* wtn1 = (__bf16*)alloc((size_t)256 * 256 * 2);
  float* gp_sum = (float*)alloc(256 * 4);
  int* deg = (int*)alloc((size_t)NN * 4);
  int* cursor = (int*)alloc((size_t)NN * 4);
  int* rowptr = (int*)alloc((size_t)(NN + 4) * 4);
  int* esrc = (int*)alloc((size_t)EE * 4);
  float2* eattr = (float2*)alloc((size_t)EE * 8);

  const int rows4 = (NN + 3) / 4;
  const dim3 gN128(1, (MP / 128));   // N=128 tiles
  const dim3 gN256(2, (MP / 128));   // N=256 tiles

  // 0. conversions
  nf_convert_kernel<<<(NN * 576 + 255) / 256, 256, 0, stream>>>(node_feature, nf_b);
  WtDescs wd;
  wd.d[0] = {Wne, wt_ne, FF, HH, 576};
  for (int l = 0; l < 4; ++l)
    wd.d[1 + l] = {W1 + (size_t)l * HH * 256, wt1 + (size_t)l * 256 * HH, HH, 256, HH};
  for (int l = 0; l < 4; ++l)
    wd.d[5 + l] = {W2 + (size_t)l * 256 * HH, wt2 + (size_t)l * HH * 256, 256, HH, 256};
  wd.d[9] = {Wn1, wtn1, 256, 256, 256};
  wt_convert_kernel<<<dim3((128 * 576 + 255) / 256, 10), 256, 0, stream>>>(wd);

  // 1. node encoder (ti-independent): x_enc = nf @ Wne + bne
  gemm_mfma<false, false><<<gN128, 256, 0, stream>>>(nf_b, wt_ne, bne, nullptr, x_enc,
                                                     NN, HH, 576);

  for (int ti = 0; ti < TT; ++ti) {
    const int* src = edge_index + (size_t)ti * 2 * EE;
    const int* dst = src + EE;
    const float* ea = edge_attr + (size_t)ti * EE * 2;

    hipMemsetAsync(deg, 0, NN * sizeof(int), stream);
    count_kernel<<<(EE + 255) / 256, 256, 0, stream>>>(dst, deg, EE);
    scan_kernel<<<1, 1024, 0, stream>>>(deg, rowptr, cursor, NN, EE);
    scatter_kernel<<<(EE + 255) / 256, 256, 0, stream>>>(src, dst, ea, cursor, esrc,
                                                         eattr, EE);

    for (int l = 0; l < LL; ++l) {
      const float* gin;
      if (l == 0) {
        gin = x_enc;
      } else {
        lnrelu_kernel<128, float><<<rows4, 256, 0, stream>>>(
            xbuf, dg + l * HH, db + l * HH, hbuf, NN, HH);
        gin = hbuf;
      }
      agg_kernel<<<rows4, 256, 0, stream>>>(gin, rowptr, esrc, eattr, Wee, bee, tpar,
                                            l, aggout_b, NN);
      gemm_mfma<false, false><<<gN256, 256, 0, stream>>>(
          aggout_b, wt1 + (size_t)l * 256 * HH, b1 + l * 2 * HH, nullptr, tmp256, NN,
          2 * HH, HH);
      lnrelu_kernel<256, __bf16><<<rows4, 256, 0, stream>>>(
          tmp256, g1 + l * 2 * HH, be1 + l * 2 * HH, t256_b, NN, 2 * HH);
      if (l == 0)
        gemm_mfma<false, false><<<gN128, 256, 0, stream>>>(
            t256_b, wt2 + (size_t)l * HH * 256, b2 + l * HH, nullptr, xbuf, NN, HH,
            256);
      else
        gemm_mfma<false, true><<<gN128, 256, 0, stream>>>(
            t256_b, wt2 + (size_t)l * HH * 256, b2 + l * HH, xbuf, xbuf, NN, HH, 256);
    }
    // final relu(LN(x; dg[0], db[0])) -> emb[:, ti, :]
    lnrelu_kernel<128, float><<<rows4, 256, 0, stream>>>(xbuf, dg, db, emb + ti * HH,
                                                         NN, 2 * HH);
  }

  // node branch
  attn_kernel<__bf16><<<rows4, 256, 0, stream>>>(emb, Wq_n, Wk_n, Wv_n, gamma_n,
                                                 attnb, NN);
  gemm_mfma<true, false><<<gN256, 256, 0, stream>>>(attnb, wtn1, bn1, nullptr, buf2,
                                                    NN, 256, 256);
  node_head_kernel<<<rows4, 256, 0, stream>>>(buf2, Wn2, bn2, out, NN);

  // graph branch
  attn_kernel<float><<<rows4, 256, 0, stream>>>(emb, Wq_g, Wk_g, Wv_g, gamma_g, buf2,
                                                NN);
  hipMemsetAsync(gp_sum, 0, 256 * sizeof(float), stream);
  pool_kernel<<<128, 256, 0, stream>>>(buf2, gp_sum, NN);
  graph_head_kernel<<<1, 256, 0, stream>>>(gp_sum, Wg1, bg1, Wg2, bg2,
                                           out + (size_t)NN * CN, 1.0f / NN);
}

// Round 3
// 743.490 us; speedup vs baseline: 2.2006x; 1.3820x over previous
//
#include <hip/hip_runtime.h>

#define NN 20000
#define TT 2
#define HH 128
#define LL 4
#define EE 320000
#define FF 514
#define CN 3
#define CG 2
#define EPS_MSG 1e-7f
#define MP 20096  // M padded (multiple of 128)

typedef __bf16 bf16x8 __attribute__((ext_vector_type(8)));
typedef __bf16 bf16x2 __attribute__((ext_vector_type(2)));
typedef float f32x4 __attribute__((ext_vector_type(4)));

// ---------------- wave helpers ----------------
__device__ inline float wave_sum(float v) {
#pragma unroll
  for (int off = 32; off; off >>= 1) v += __shfl_xor(v, off);
  return v;
}

__device__ __forceinline__ void gload_lds16(const void* g, void* l) {
  __builtin_amdgcn_global_load_lds(
      (const __attribute__((address_space(1))) unsigned int*)g,
      (__attribute__((address_space(3))) unsigned int*)l, 16, 0, 0);
}

// ---------------- bf16 MFMA GEMM: C = A[M,K]@BT[N,K]^T + bias (+D)(+relu) ----
// BM=64, BN=128, BK=32, double-buffered LDS, one barrier per K-step.
// A: bf16 [rows padded to >=bm+64][K], K%32==0. BT: bf16 [N][K], N%128==0.
template <bool RELU, bool ADD, typename OT>
__global__ __launch_bounds__(256) void gemm_mfma(
    const __bf16* __restrict__ A, const __bf16* __restrict__ BT,
    const float* __restrict__ bias, const float* __restrict__ D,
    OT* __restrict__ C, int M, int N, int K) {
  __shared__ __bf16 As[2][64][32];
  __shared__ __bf16 Bs[2][128][32];
  const int tid = threadIdx.x;
  const int lane = tid & 63, w = tid >> 6;
  const int bm = blockIdx.y * 64, bn = blockIdx.x * 128;
  const int wr = (w >> 1) * 32, wc = (w & 1) * 64;
  const int fr = lane & 15, fq = lane >> 4;
  // staging: thread -> (row tid/4, 16B chunk tid%4); LDS byte off = tid*16 (wave-linear)
  const int rowA = tid >> 2, chA = (tid & 3) * 8;
  const __bf16* Ab = A + (size_t)(bm + rowA) * K + chA;
  const __bf16* Bb = BT + (size_t)(bn + rowA) * K + chA;
  const __bf16* Bb2 = Bb + (size_t)64 * K;
  f32x4 acc[2][4] = {};

#define STAGE(buf, k0)                                  \
  do {                                                  \
    gload_lds16(Ab + (k0), &As[buf][rowA][chA]);        \
    gload_lds16(Bb + (k0), &Bs[buf][rowA][chA]);        \
    gload_lds16(Bb2 + (k0), &Bs[buf][rowA + 64][chA]);  \
  } while (0)

  STAGE(0, 0);
  __syncthreads();
  int cur = 0;
  for (int k0 = 0; k0 < K; k0 += 32) {
    if (k0 + 32 < K) STAGE(cur ^ 1, k0 + 32);  // loads fly during MFMA below
    bf16x8 af[2], bq[4];
#pragma unroll
    for (int m = 0; m < 2; ++m)
      af[m] = *(const bf16x8*)&As[cur][wr + m * 16 + fr][fq * 8];
#pragma unroll
    for (int n = 0; n < 4; ++n)
      bq[n] = *(const bf16x8*)&Bs[cur][wc + n * 16 + fr][fq * 8];
#pragma unroll
    for (int m = 0; m < 2; ++m)
#pragma unroll
      for (int n = 0; n < 4; ++n)
        acc[m][n] =
            __builtin_amdgcn_mfma_f32_16x16x32_bf16(af[m], bq[n], acc[m][n], 0, 0, 0);
    __syncthreads();  // drains next-tile loads + all reads of cur
    cur ^= 1;
  }
#undef STAGE

#pragma unroll
  for (int m = 0; m < 2; ++m) {
#pragma unroll
    for (int n = 0; n < 4; ++n) {
#pragma unroll
      for (int j = 0; j < 4; ++j) {
        int gm = bm + wr + m * 16 + fq * 4 + j;
        int gn = bn + wc + n * 16 + fr;
        if (gm < M) {
          float c = acc[m][n][j] + bias[gn];
          if (ADD) c += D[(size_t)gm * N + gn];
          if (RELU) c = fmaxf(c, 0.f);
          C[(size_t)gm * N + gn] = (OT)c;
        }
      }
    }
  }
}

// ---------------- conversions ----------------
__global__ void nf_convert_kernel(const float* __restrict__ src, __bf16* __restrict__ dst) {
  int idx = blockIdx.x * 256 + threadIdx.x;
  if (idx >= NN * 576) return;
  int row = idx / 576, col = idx - row * 576;
  float v = (col < FF) ? src[(size_t)row * FF + col] : 0.f;
  dst[idx] = (__bf16)v;
}

struct WtDesc { const float* src; __bf16* dst; int K, N, Kpad; };
struct WtDescs { WtDesc d[10]; };

__global__ void wt_convert_kernel(WtDescs descs) {
  WtDesc de = descs.d[blockIdx.y];
  int idx = blockIdx.x * 256 + threadIdx.x;
  if (idx >= de.N * de.Kpad) return;
  int n = idx / de.Kpad, k = idx - n * de.Kpad;
  float v = (k < de.K) ? de.src[(size_t)k * de.N + n] : 0.f;
  de.dst[idx] = (__bf16)v;
}

// ---------------- row LayerNorm + ReLU (wave per row) ----------------
template <int W, typename OT>
__global__ __launch_bounds__(256) void lnrelu_kernel(
    const float* __restrict__ X, const float* __restrict__ g,
    const float* __restrict__ b, OT* __restrict__ Y, int rows, int ostride) {
  int wave = threadIdx.x >> 6, lane = threadIdx.x & 63;
  int n = blockIdx.x * 4 + wave;
  if (n >= rows) return;
  constexpr int C = W / 64;
  float v[C];
  const float* rowp = X + (size_t)n * W + lane * C;
  if constexpr (C == 2) {
    float2 t2 = *(const float2*)rowp;
    v[0] = t2.x; v[1] = t2.y;
  } else {
    float4 t4 = *(const float4*)rowp;
    v[0] = t4.x; v[1] = t4.y; v[2] = t4.z; v[3] = t4.w;
  }
  float s = 0.f, s2 = 0.f;
#pragma unroll
  for (int i = 0; i < C; ++i) { s += v[i]; s2 += v[i] * v[i]; }
  s = wave_sum(s);
  s2 = wave_sum(s2);
  float mu = s * (1.f / W);
  float var = fmaxf(s2 * (1.f / W) - mu * mu, 0.f);
  float r = rsqrtf(var + 1e-5f);
  OT ov[C];
#pragma unroll
  for (int i = 0; i < C; ++i) {
    float gv = g[lane * C + i], bv = b[lane * C + i];
    float y = (v[i] - mu) * r * gv + bv;
    ov[i] = (OT)fmaxf(y, 0.f);
  }
  OT* op = Y + (size_t)n * ostride + lane * C;
  __builtin_memcpy(op, ov, sizeof(ov));
}

// ---------------- CSR build (both ti fused) ----------------
__global__ void count2_kernel(const int* __restrict__ edge_index, int* __restrict__ deg) {
  int i = blockIdx.x * 256 + threadIdx.x;
  if (i >= 2 * EE) return;
  int ti = (i >= EE) ? 1 : 0;
  int e = i - ti * EE;
  int d = edge_index[(size_t)ti * 2 * EE + EE + e];
  atomicAdd(&deg[ti * NN + d], 1);
}

__global__ __launch_bounds__(1024) void scan2_kernel(
    const int* __restrict__ deg_all, int* __restrict__ rowptr_all,
    int* __restrict__ cursor_all) {
  const int ti = blockIdx.x;
  const int* deg = deg_all + ti * NN;
  int* rowptr = rowptr_all + ti * (NN + 1);
  int* cursor = cursor_all + ti * NN;
  __shared__ int sums[1024];
  int tid = threadIdx.x;
  int chunk = (NN + 1023) / 1024;
  int begin = tid * chunk, end = min(begin + chunk, NN);
  int s = 0;
  for (int i = begin; i < end; ++i) s += deg[i];
  sums[tid] = s;
  __syncthreads();
  for (int off = 1; off < 1024; off <<= 1) {
    int v = (tid >= off) ? sums[tid - off] : 0;
    __syncthreads();
    sums[tid] += v;
    __syncthreads();
  }
  int running = sums[tid] - s;  // exclusive prefix
  for (int i = begin; i < end; ++i) {
    rowptr[i] = running;
    cursor[i] = running;
    running += deg[i];
  }
  if (tid == 0) rowptr[NN] = EE;
}

__global__ void scatter2_kernel(const int* __restrict__ edge_index,
                                const float* __restrict__ edge_attr,
                                int* __restrict__ cursor_all, int* __restrict__ esrc_all,
                                float2* __restrict__ eattr_all) {
  int i = blockIdx.x * 256 + threadIdx.x;
  if (i >= 2 * EE) return;
  int ti = (i >= EE) ? 1 : 0;
  int e = i - ti * EE;
  const int* srcp = edge_index + (size_t)ti * 2 * EE;
  int s = srcp[e], d = srcp[EE + e];
  float2 ea = ((const float2*)edge_attr)[(size_t)ti * EE + e];
  int pos = atomicAdd(&cursor_all[ti * NN + d], 1);
  esrc_all[(size_t)ti * EE + pos] = s;
  eattr_all[(size_t)ti * EE + pos] = ea;
}

// ---------------- GENConv softmax aggregation + residual (bf16 in/out) -----
// out[n,:] = sum_j msg_j * softmax_j(msg_j*t) + xin[n,:]
// msg = relu(x[src] + ea@Wee + bee) + EPS. 2-edge unroll for MLP.
__global__ __launch_bounds__(256) void agg_kernel(
    const __bf16* __restrict__ xin, const int* __restrict__ rowptr,
    const int* __restrict__ esrc, const float2* __restrict__ eattr,
    const float* __restrict__ Wee, const float* __restrict__ bee,
    const float* __restrict__ tptr, int layer, __bf16* __restrict__ out, int nNodes) {
  int wave = threadIdx.x >> 6, lane = threadIdx.x & 63;
  int n = blockIdx.x * 4 + wave;
  if (n >= nNodes) return;
  float t = tptr[layer];
  int c0 = lane * 2;
  float w00 = Wee[c0], w01 = Wee[c0 + 1];
  float w10 = Wee[HH + c0], w11 = Wee[HH + c0 + 1];
  float be0 = bee[c0], be1 = bee[c0 + 1];
  float denA0 = 0.f, denA1 = 0.f, numA0 = 0.f, numA1 = 0.f;
  float denB0 = 0.f, denB1 = 0.f, numB0 = 0.f, numB1 = 0.f;
  int e = rowptr[n], e1 = rowptr[n + 1];
  for (; e + 2 <= e1; e += 2) {
    int s0 = esrc[e], s1 = esrc[e + 1];
    float2 ea0 = eattr[e], ea1 = eattr[e + 1];
    bf16x2 xv0 = *(const bf16x2*)(xin + (size_t)s0 * HH + c0);
    bf16x2 xv1 = *(const bf16x2*)(xin + (size_t)s1 * HH + c0);
    float ma0 = (float)xv0[0] + ea0.x * w00 + ea0.y * w10 + be0;
    float ma1 = (float)xv0[1] + ea0.x * w01 + ea0.y * w11 + be1;
    ma0 = fmaxf(ma0, 0.f) + EPS_MSG;
    ma1 = fmaxf(ma1, 0.f) + EPS_MSG;
    float exa0 = __expf(ma0 * t), exa1 = __expf(ma1 * t);
    denA0 += exa0; denA1 += exa1;
    numA0 += ma0 * exa0; numA1 += ma1 * exa1;
    float mb0 = (float)xv1[0] + ea1.x * w00 + ea1.y * w10 + be0;
    float mb1 = (float)xv1[1] + ea1.x * w01 + ea1.y * w11 + be1;
    mb0 = fmaxf(mb0, 0.f) + EPS_MSG;
    mb1 = fmaxf(mb1, 0.f) + EPS_MSG;
    float exb0 = __expf(mb0 * t), exb1 = __expf(mb1 * t);
    denB0 += exb0; denB1 += exb1;
    numB0 += mb0 * exb0; numB1 += mb1 * exb1;
  }
  if (e < e1) {
    int s0 = esrc[e];
    float2 ea0 = eattr[e];
    bf16x2 xv0 = *(const bf16x2*)(xin + (size_t)s0 * HH + c0);
    float ma0 = (float)xv0[0] + ea0.x * w00 + ea0.y * w10 + be0;
    float ma1 = (float)xv0[1] + ea0.x * w01 + ea0.y * w11 + be1;
    ma0 = fmaxf(ma0, 0.f) + EPS_MSG;
    ma1 = fmaxf(ma1, 0.f) + EPS_MSG;
    float exa0 = __expf(ma0 * t), exa1 = __expf(ma1 * t);
    denA0 += exa0; denA1 += exa1;
    numA0 += ma0 * exa0; numA1 += ma1 * exa1;
  }
  float den0 = denA0 + denB0, den1 = denA1 + denB1;
  float num0 = numA0 + numB0, num1 = numA1 + numB1;
  bf16x2 xr = *(const bf16x2*)(xin + (size_t)n * HH + c0);
  bf16x2 o;
  o[0] = (__bf16)(num0 / (den0 + 1e-16f) + (float)xr[0]);
  o[1] = (__bf16)(num1 / (den1 + 1e-16f) + (float)xr[1]);
  *(bf16x2*)(out + (size_t)n * HH + c0) = o;
}

// ---------------- channel attention over T=2 (wave per node) ----------------
template <typename OT>
__global__ __launch_bounds__(256) void attn_kernel(
    const float* __restrict__ emb, const float* __restrict__ Wq,
    const float* __restrict__ Wk, const float* __restrict__ Wv,
    const float* __restrict__ gammap, OT* __restrict__ out, int nNodes) {
  int wave = threadIdx.x >> 6, lane = threadIdx.x & 63;
  int n = blockIdx.x * 4 + wave;
  if (n >= nNodes) return;
  float gamma = *gammap;
  float wq00 = Wq[0], wq01 = Wq[1], wq10 = Wq[2], wq11 = Wq[3];
  float wk00 = Wk[0], wk01 = Wk[1], wk10 = Wk[2], wk11 = Wk[3];
  float wv00 = Wv[0], wv01 = Wv[1], wv10 = Wv[2], wv11 = Wv[3];
  int c0 = lane * 2;
  const float* base = emb + (size_t)n * (2 * HH);
  float2 x0 = *(const float2*)(base + c0);
  float2 x1 = *(const float2*)(base + HH + c0);
  float q0a = wq00 * x0.x + wq01 * x1.x, q0b = wq00 * x0.y + wq01 * x1.y;
  float q1a = wq10 * x0.x + wq11 * x1.x, q1b = wq10 * x0.y + wq11 * x1.y;
  float k0a = wk00 * x0.x + wk01 * x1.x, k0b = wk00 * x0.y + wk01 * x1.y;
  float k1a = wk10 * x0.x + wk11 * x1.x, k1b = wk10 * x0.y + wk11 * x1.y;
  float v0a = wv00 * x0.x + wv01 * x1.x, v0b = wv00 * x0.y + wv01 * x1.y;
  float v1a = wv10 * x0.x + wv11 * x1.x, v1b = wv10 * x0.y + wv11 * x1.y;
  float s00 = wave_sum(q0a * k0a + q0b * k0b);
  float s01 = wave_sum(q0a * k1a + q0b * k1b);
  float s10 = wave_sum(q1a * k0a + q1b * k0b);
  float s11 = wave_sum(q1a * k1a + q1b * k1b);
  float m0 = fmaxf(s00, s01);
  float e00 = __expf(s00 - m0), e01 = __expf(s01 - m0);
  float i0 = 1.f / (e00 + e01);
  float a00 = e00 * i0, a01 = e01 * i0;
  float m1 = fmaxf(s10, s11);
  float e10 = __expf(s10 - m1), e11 = __expf(s11 - m1);
  float i1 = 1.f / (e10 + e11);
  float a10 = e10 * i1, a11 = e11 * i1;
  OT* op = out + (size_t)n * (2 * HH);
  op[c0] = (OT)(gamma * (a00 * v0a + a01 * v1a) + x0.x);
  op[c0 + 1] = (OT)(gamma * (a00 * v0b + a01 * v1b) + x0.y);
  op[HH + c0] = (OT)(gamma * (a10 * v0a + a11 * v1a) + x1.x);
  op[HH + c0 + 1] = (OT)(gamma * (a10 * v0b + a11 * v1b) + x1.y);
}

// ---------------- node head: logits3 + log_softmax (wave per node) ----------
__global__ __launch_bounds__(256) void node_head_kernel(
    const float* __restrict__ tmp, const float* __restrict__ Wn2,
    const float* __restrict__ bn2, float* __restrict__ outp, int nNodes) {
  int wave = threadIdx.x >> 6, lane = threadIdx.x & 63;
  int n = blockIdx.x * 4 + wave;
  if (n >= nNodes) return;
  const float* row = tmp + (size_t)n * 256;
  float4 xv = *(const float4*)(row + lane * 4);
  float xs[4] = {xv.x, xv.y, xv.z, xv.w};
  float p0 = 0.f, p1 = 0.f, p2 = 0.f;
#pragma unroll
  for (int i = 0; i < 4; ++i) {
    int c = lane * 4 + i;
    p0 += xs[i] * Wn2[c * 3 + 0];
    p1 += xs[i] * Wn2[c * 3 + 1];
    p2 += xs[i] * Wn2[c * 3 + 2];
  }
  p0 = wave_sum(p0); p1 = wave_sum(p1); p2 = wave_sum(p2);
  if (lane == 0) {
    float l0 = p0 + bn2[0], l1 = p1 + bn2[1], l2 = p2 + bn2[2];
    float m = fmaxf(l0, fmaxf(l1, l2));
    float lse = m + logf(__expf(l0 - m) + __expf(l1 - m) + __expf(l2 - m));
    outp[(size_t)n * 3 + 0] = l0 - lse;
    outp[(size_t)n * 3 + 1] = l1 - lse;
    outp[(size_t)n * 3 + 2] = l2 - lse;
  }
}

// ---------------- mean pool ----------------
__global__ __launch_bounds__(256) void pool_kernel(const float* __restrict__ gbuf,
                                                   float* __restrict__ gp_sum, int nNodes) {
  int c = threadIdx.x;
  float s = 0.f;
  for (int r = blockIdx.x; r < nNodes; r += gridDim.x) s += gbuf[(size_t)r * 256 + c];
  atomicAdd(&gp_sum[c], s);
}

// ---------------- graph head (single block) ----------------
__global__ __launch_bounds__(256) void graph_head_kernel(
    const float* __restrict__ gp_sum, const float* __restrict__ Wg1,
    const float* __restrict__ bg1, const float* __restrict__ Wg2,
    const float* __restrict__ bg2, float* __restrict__ outp, float invN) {
  __shared__ float gp[256];
  __shared__ float h1[256];
  __shared__ float lg[2];
  int tid = threadIdx.x;
  gp[tid] = gp_sum[tid] * invN;
  __syncthreads();
  float acc = bg1[tid];
  for (int k = 0; k < 256; ++k) acc += gp[k] * Wg1[k * 256 + tid];
  h1[tid] = fmaxf(acc, 0.f);
  __syncthreads();
  if (tid < 2) {
    float l = bg2[tid];
    for (int c = 0; c < 256; ++c) l += h1[c] * Wg2[c * 2 + tid];
    lg[tid] = l;
  }
  __syncthreads();
  if (tid == 0) {
    float m = fmaxf(lg[0], lg[1]);
    float lse = m + logf(__expf(lg[0] - m) + __expf(lg[1] - m));
    outp[0] = lg[0] - lse;
    outp[1] = lg[1] - lse;
  }
}

// ---------------- launch ----------------
extern "C" void kernel_launch(void* const* d_in, const int* in_sizes, int n_in,
                              void* d_out, int out_size, void* d_ws, size_t ws_size,
                              hipStream_t stream) {
  (void)in_sizes; (void)n_in; (void)out_size; (void)ws_size;
  const float* node_feature = (const float*)d_in[0];
  const int* edge_index = (const int*)d_in[1];
  const float* edge_attr = (const float*)d_in[2];
  const float* Wne = (const float*)d_in[3];
  const float* bne = (const float*)d_in[4];
  const float* Wee = (const float*)d_in[5];
  const float* bee = (const float*)d_in[6];
  const float* W1 = (const float*)d_in[7];
  const float* b1 = (const float*)d_in[8];
  const float* g1 = (const float*)d_in[9];
  const float* be1 = (const float*)d_in[10];
  const float* W2 = (const float*)d_in[11];
  const float* b2 = (const float*)d_in[12];
  const float* dg = (const float*)d_in[13];
  const float* db = (const float*)d_in[14];
  const float* tpar = (const float*)d_in[15];
  const float* Wq_n = (const float*)d_in[16];
  const float* Wk_n = (const float*)d_in[17];
  const float* Wv_n = (const float*)d_in[18];
  const float* gamma_n = (const float*)d_in[19];
  const float* Wn1 = (const float*)d_in[20];
  const float* bn1 = (const float*)d_in[21];
  const float* Wn2 = (const float*)d_in[22];
  const float* bn2 = (const float*)d_in[23];
  const float* Wq_g = (const float*)d_in[24];
  const float* Wk_g = (const float*)d_in[25];
  const float* Wv_g = (const float*)d_in[26];
  const float* gamma_g = (const float*)d_in[27];
  const float* Wg1 = (const float*)d_in[28];
  const float* bg1 = (const float*)d_in[29];
  const float* Wg2 = (const float*)d_in[30];
  const float* bg2 = (const float*)d_in[31];
  float* out = (float*)d_out;

  // ---- workspace carve-out (256B-aligned regions) ----
  char* pc = (char*)d_ws;
  auto alloc = [&](size_t bytes) {
    char* r = pc;
    pc += (bytes + 255) & ~(size_t)255;
    return r;
  };
  float* xbuf = (float*)alloc((size_t)NN * HH * 4);          // f32 residual chain
  __bf16* hbuf_b = (__bf16*)alloc((size_t)MP * HH * 2);      // LN'd agg input
  float* tmp256 = (float*)alloc((size_t)NN * 2 * HH * 4);    // lin1 out / head tmp
  float* buf2 = tmp256;                                      // alias (disjoint in time)
  float* emb = (float*)alloc((size_t)NN * 2 * HH * 4);
  __bf16* aggout_b = (__bf16*)alloc((size_t)MP * HH * 2);
  __bf16* t256_b = (__bf16*)alloc((size_t)MP * 2 * HH * 2);
  __bf16* attnb = t256_b;  // alias: node-attn bf16 out (after last lin2)
  // nf_b aliases emb + spills into aggout_b: 20096*576*2=23.2MB <= 20.48+5.15MB
  __bf16* nf_b = (__bf16*)emb;
  __bf16* x_enc_b = (__bf16*)alloc((size_t)MP * HH * 2);
  __bf16* wt_ne = (__bf16*)alloc((size_t)128 * 576 * 2);
  __bf16* wt1 = (__bf16*)alloc((size_t)4 * 256 * 128 * 2);
  __bf16* wt2 = (__bf16*)alloc((size_t)4 * 128 * 256 * 2);
  __bf16* wtn1 = (__bf16*)alloc((size_t)256 * 256 * 2);
  float* gp_sum = (float*)alloc(256 * 4);
  int* deg = (int*)alloc((size_t)2 * NN * 4);
  int* cursor = (int*)alloc((size_t)2 * NN * 4);
  int* rowptr = (int*)alloc((size_t)2 * (NN + 1) * 4 + 8);
  int* esrc = (int*)alloc((size_t)2 * EE * 4);
  float2* eattr = (float2*)alloc((size_t)2 * EE * 8);

  const int rows4 = (NN + 3) / 4;
  const dim3 gN128(1, MP / 64);   // 314 blocks, N=128
  const dim3 gN256(2, MP / 64);   // 628 blocks, N=256

  // 0. conversions
  nf_convert_kernel<<<(NN * 576 + 255) / 256, 256, 0, stream>>>(node_feature, nf_b);
  WtDescs wd;
  wd.d[0] = {Wne, wt_ne, FF, HH, 576};
  for (int l = 0; l < 4; ++l)
    wd.d[1 + l] = {W1 + (size_t)l * HH * 256, wt1 + (size_t)l * 256 * HH, HH, 256, HH};
  for (int l = 0; l < 4; ++l)
    wd.d[5 + l] = {W2 + (size_t)l * 256 * HH, wt2 + (size_t)l * HH * 256, 256, HH, 256};
  wd.d[9] = {Wn1, wtn1, 256, 256, 256};
  wt_convert_kernel<<<dim3((128 * 576 + 255) / 256, 10), 256, 0, stream>>>(wd);

  // CSR for both ti
  hipMemsetAsync(deg, 0, 2 * NN * sizeof(int), stream);
  count2_kernel<<<(2 * EE + 255) / 256, 256, 0, stream>>>(edge_index, deg);
  scan2_kernel<<<2, 1024, 0, stream>>>(deg, rowptr, cursor);
  scatter2_kernel<<<(2 * EE + 255) / 256, 256, 0, stream>>>(edge_index, edge_attr,
                                                            cursor, esrc, eattr);

  // 1. node encoder (ti-independent): x_enc_b = bf16(nf @ Wne + bne)
  gemm_mfma<false, false, __bf16><<<gN128, 256, 0, stream>>>(nf_b, wt_ne, bne, nullptr,
                                                             x_enc_b, NN, HH, 576);

  for (int ti = 0; ti < TT; ++ti) {
    const int* rp = rowptr + ti * (NN + 1);
    const int* es = esrc + (size_t)ti * EE;
    const float2* ez = eattr + (size_t)ti * EE;

    for (int l = 0; l < LL; ++l) {
      const __bf16* gin;
      if (l == 0) {
        gin = x_enc_b;
      } else {
        lnrelu_kernel<128, __bf16><<<rows4, 256, 0, stream>>>(
            xbuf, dg + l * HH, db + l * HH, hbuf_b, NN, HH);
        gin = hbuf_b;
      }
      agg_kernel<<<rows4, 256, 0, stream>>>(gin, rp, es, ez, Wee, bee, tpar, l,
                                            aggout_b, NN);
      gemm_mfma<false, false, float><<<gN256, 256, 0, stream>>>(
          aggout_b, wt1 + (size_t)l * 256 * HH, b1 + l * 2 * HH, nullptr, tmp256, NN,
          2 * HH, HH);
      lnrelu_kernel<256, __bf16><<<rows4, 256, 0, stream>>>(
          tmp256, g1 + l * 2 * HH, be1 + l * 2 * HH, t256_b, NN, 2 * HH);
      if (l == 0)
        gemm_mfma<false, false, float><<<gN128, 256, 0, stream>>>(
            t256_b, wt2 + (size_t)l * HH * 256, b2 + l * HH, nullptr, xbuf, NN, HH,
            256);
      else
        gemm_mfma<false, true, float><<<gN128, 256, 0, stream>>>(
            t256_b, wt2 + (size_t)l * HH * 256, b2 + l * HH, xbuf, xbuf, NN, HH, 256);
    }
    // final relu(LN(x; dg[0], db[0])) -> emb[:, ti, :]
    lnrelu_kernel<128, float><<<rows4, 256, 0, stream>>>(xbuf, dg, db, emb + ti * HH,
                                                         NN, 2 * HH);
  }

  // node branch
  attn_kernel<__bf16><<<rows4, 256, 0, stream>>>(emb, Wq_n, Wk_n, Wv_n, gamma_n,
                                                 attnb, NN);
  gemm_mfma<true, false, float><<<gN256, 256, 0, stream>>>(attnb, wtn1, bn1, nullptr,
                                                           buf2, NN, 256, 256);
  node_head_kernel<<<rows4, 256, 0, stream>>>(buf2, Wn2, bn2, out, NN);

  // graph branch
  attn_kernel<float><<<rows4, 256, 0, stream>>>(emb, Wq_g, Wk_g, Wv_g, gamma_g, buf2,
                                                NN);
  hipMemsetAsync(gp_sum, 0, 256 * sizeof(float), stream);
  pool_kernel<<<128, 256, 0, stream>>>(buf2, gp_sum, NN);
  graph_head_kernel<<<1, 256, 0, stream>>>(gp_sum, Wg1, bg1, Wg2, bg2,
                                           out + (size_t)NN * CN, 1.0f / NN);
}

// Round 4
// 643.937 us; speedup vs baseline: 2.5408x; 1.1546x over previous
//
#include <hip/hip_runtime.h>

#define NN 20000
#define TT 2
#define HH 128
#define LL 4
#define EE 320000
#define FF 514
#define CN 3
#define CG 2
#define EPS_MSG 1e-7f
#define MP 20096  // M padded (multiple of 128)

typedef __bf16 bf16x8 __attribute__((ext_vector_type(8)));
typedef __bf16 bf16x2 __attribute__((ext_vector_type(2)));
typedef float f32x4 __attribute__((ext_vector_type(4)));

struct __align__(8) Edge { int src; __bf16 ea0, ea1; };

// ---------------- wave helpers ----------------
__device__ inline float wave_sum(float v) {
#pragma unroll
  for (int off = 32; off; off >>= 1) v += __shfl_xor(v, off);
  return v;
}
__device__ inline float red16(float v) {  // reduce across fr = lane&15
  v += __shfl_xor(v, 1); v += __shfl_xor(v, 2);
  v += __shfl_xor(v, 4); v += __shfl_xor(v, 8);
  return v;
}

__device__ __forceinline__ void gload_lds16(const void* g, void* l) {
  __builtin_amdgcn_global_load_lds(
      (const __attribute__((address_space(1))) unsigned int*)g,
      (__attribute__((address_space(3))) unsigned int*)l, 16, 0, 0);
}

// ---------------- generic bf16 MFMA GEMM (BM=64,BN=128,BK=32, dbuf) --------
// C = A[M,K]@BT[N,K]^T + bias (+D)(+relu). A rows padded >= bm+64, K%32==0.
template <bool RELU, bool ADD, typename OT>
__global__ __launch_bounds__(256) void gemm_mfma(
    const __bf16* __restrict__ A, const __bf16* __restrict__ BT,
    const float* __restrict__ bias, const float* __restrict__ D,
    OT* __restrict__ C, int M, int N, int K) {
  __shared__ __bf16 As[2][64][32];
  __shared__ __bf16 Bs[2][128][32];
  const int tid = threadIdx.x;
  const int lane = tid & 63, w = tid >> 6;
  const int bm = blockIdx.y * 64, bn = blockIdx.x * 128;
  const int wr = (w >> 1) * 32, wc = (w & 1) * 64;
  const int fr = lane & 15, fq = lane >> 4;
  const int rowA = tid >> 2, chA = (tid & 3) * 8;
  const __bf16* Ab = A + (size_t)(bm + rowA) * K + chA;
  const __bf16* Bb = BT + (size_t)(bn + rowA) * K + chA;
  const __bf16* Bb2 = Bb + (size_t)64 * K;
  f32x4 acc[2][4] = {};

#define STAGE(buf, k0)                                  \
  do {                                                  \
    gload_lds16(Ab + (k0), &As[buf][rowA][chA]);        \
    gload_lds16(Bb + (k0), &Bs[buf][rowA][chA]);        \
    gload_lds16(Bb2 + (k0), &Bs[buf][rowA + 64][chA]);  \
  } while (0)

  STAGE(0, 0);
  __syncthreads();
  int cur = 0;
  for (int k0 = 0; k0 < K; k0 += 32) {
    if (k0 + 32 < K) STAGE(cur ^ 1, k0 + 32);
    bf16x8 af[2], bq[4];
#pragma unroll
    for (int m = 0; m < 2; ++m)
      af[m] = *(const bf16x8*)&As[cur][wr + m * 16 + fr][fq * 8];
#pragma unroll
    for (int n = 0; n < 4; ++n)
      bq[n] = *(const bf16x8*)&Bs[cur][wc + n * 16 + fr][fq * 8];
#pragma unroll
    for (int m = 0; m < 2; ++m)
#pragma unroll
      for (int n = 0; n < 4; ++n)
        acc[m][n] =
            __builtin_amdgcn_mfma_f32_16x16x32_bf16(af[m], bq[n], acc[m][n], 0, 0, 0);
    __syncthreads();
    cur ^= 1;
  }
#undef STAGE

#pragma unroll
  for (int m = 0; m < 2; ++m) {
#pragma unroll
    for (int n = 0; n < 4; ++n) {
#pragma unroll
      for (int j = 0; j < 4; ++j) {
        int gm = bm + wr + m * 16 + fq * 4 + j;
        int gn = bn + wc + n * 16 + fr;
        if (gm < M) {
          float c = acc[m][n][j] + bias[gn];
          if (ADD) c += D[(size_t)gm * N + gn];
          if (RELU) c = fmaxf(c, 0.f);
          C[(size_t)gm * N + gn] = (OT)c;
        }
      }
    }
  }
}

// ---------------- fused 256-wide GEMM (BM=64, BN=256, full row per wave) ----
// EPI 0: LN(c; g,be) -> relu -> bf16 out [MP][256]
// EPI 1: relu(c) -> @W2h[256,3] + b2h -> log_softmax -> f32 out [M][3]
template <int EPI>
__global__ __launch_bounds__(256) void gemm256(
    const __bf16* __restrict__ A, const __bf16* __restrict__ BT,
    const float* __restrict__ bias, const float* __restrict__ g,
    const float* __restrict__ be, const float* __restrict__ W2h,
    const float* __restrict__ b2h, void* __restrict__ outp, int M, int K) {
  __shared__ __bf16 As[2][64][32];
  __shared__ __bf16 Bs[2][256][32];
  const int tid = threadIdx.x;
  const int lane = tid & 63, w = tid >> 6;
  const int bm = blockIdx.x * 64;
  const int wr = w * 16;
  const int fr = lane & 15, fq = lane >> 4;
  const int rowA = tid >> 2, chA = (tid & 3) * 8;
  const __bf16* Ab = A + (size_t)(bm + rowA) * K + chA;
  const __bf16* Bb = BT + (size_t)rowA * K + chA;
  f32x4 acc[16] = {};

#define STG(buf, k0)                                                \
  do {                                                              \
    gload_lds16(Ab + (k0), &As[buf][rowA][chA]);                    \
    _Pragma("unroll") for (int r = 0; r < 4; ++r)                   \
        gload_lds16(Bb + (size_t)(r * 64) * K + (k0),               \
                    &Bs[buf][rowA + r * 64][chA]);                  \
  } while (0)

  STG(0, 0);
  __syncthreads();
  int cur = 0;
  for (int k0 = 0; k0 < K; k0 += 32) {
    if (k0 + 32 < K) STG(cur ^ 1, k0 + 32);
    bf16x8 af = *(const bf16x8*)&As[cur][wr + fr][fq * 8];
#pragma unroll
    for (int n = 0; n < 16; ++n) {
      bf16x8 bq = *(const bf16x8*)&Bs[cur][n * 16 + fr][fq * 8];
      acc[n] = __builtin_amdgcn_mfma_f32_16x16x32_bf16(af, bq, acc[n], 0, 0, 0);
    }
    __syncthreads();
    cur ^= 1;
  }
#undef STG

  float cb[16];
#pragma unroll
  for (int n = 0; n < 16; ++n) cb[n] = bias[n * 16 + fr];

  if constexpr (EPI == 0) {
    float gv[16], bev[16];
#pragma unroll
    for (int n = 0; n < 16; ++n) {
      gv[n] = g[n * 16 + fr];
      bev[n] = be[n * 16 + fr];
    }
    __bf16* outb = (__bf16*)outp;
#pragma unroll
    for (int j = 0; j < 4; ++j) {
      float cj[16], s = 0.f, s2 = 0.f;
#pragma unroll
      for (int n = 0; n < 16; ++n) {
        float c = acc[n][j] + cb[n];
        cj[n] = c; s += c; s2 += c * c;
      }
      s = red16(s); s2 = red16(s2);
      float mu = s * (1.f / 256);
      float var = fmaxf(s2 * (1.f / 256) - mu * mu, 0.f);
      float rr = rsqrtf(var + 1e-5f);
      int gm = bm + wr + fq * 4 + j;
      __bf16* op = outb + (size_t)gm * 256;
#pragma unroll
      for (int n = 0; n < 16; ++n) {
        float y = (cj[n] - mu) * rr * gv[n] + bev[n];
        op[n * 16 + fr] = (__bf16)fmaxf(y, 0.f);
      }
    }
  } else {
    float w0[16], w1[16], w2[16];
#pragma unroll
    for (int n = 0; n < 16; ++n) {
      int col = n * 16 + fr;
      w0[n] = W2h[col * 3 + 0];
      w1[n] = W2h[col * 3 + 1];
      w2[n] = W2h[col * 3 + 2];
    }
    float* outf = (float*)outp;
#pragma unroll
    for (int j = 0; j < 4; ++j) {
      float p0 = 0.f, p1 = 0.f, p2 = 0.f;
#pragma unroll
      for (int n = 0; n < 16; ++n) {
        float h = fmaxf(acc[n][j] + cb[n], 0.f);
        p0 += h * w0[n]; p1 += h * w1[n]; p2 += h * w2[n];
      }
      p0 = red16(p0); p1 = red16(p1); p2 = red16(p2);
      int gm = bm + wr + fq * 4 + j;
      if (fr == 0 && gm < M) {
        float l0 = p0 + b2h[0], l1 = p1 + b2h[1], l2 = p2 + b2h[2];
        float m = fmaxf(l0, fmaxf(l1, l2));
        float lse = m + logf(__expf(l0 - m) + __expf(l1 - m) + __expf(l2 - m));
        outf[(size_t)gm * 3 + 0] = l0 - lse;
        outf[(size_t)gm * 3 + 1] = l1 - lse;
        outf[(size_t)gm * 3 + 2] = l2 - lse;
      }
    }
  }
}

// ---------------- conversions ----------------
__global__ void nf_convert_kernel(const float* __restrict__ src, __bf16* __restrict__ dst) {
  int idx = blockIdx.x * 256 + threadIdx.x;
  if (idx >= NN * 576) return;
  int row = idx / 576, col = idx - row * 576;
  float v = (col < FF) ? src[(size_t)row * FF + col] : 0.f;
  dst[idx] = (__bf16)v;
}

struct WtDesc { const float* src; __bf16* dst; int K, N, Kpad; };
struct WtDescs { WtDesc d[10]; };

__global__ void wt_convert_kernel(WtDescs descs) {
  WtDesc de = descs.d[blockIdx.y];
  int idx = blockIdx.x * 256 + threadIdx.x;
  if (idx >= de.N * de.Kpad) return;
  int n = idx / de.Kpad, k = idx - n * de.Kpad;
  float v = (k < de.K) ? de.src[(size_t)k * de.N + n] : 0.f;
  de.dst[idx] = (__bf16)v;
}

// ---------------- row LayerNorm + ReLU (wave per row, W=128) ----------------
template <typename OT>
__global__ __launch_bounds__(256) void lnrelu128_kernel(
    const float* __restrict__ X, const float* __restrict__ g,
    const float* __restrict__ b, OT* __restrict__ Y, int rows, int ostride) {
  int wave = threadIdx.x >> 6, lane = threadIdx.x & 63;
  int n = blockIdx.x * 4 + wave;
  if (n >= rows) return;
  float2 t2 = *(const float2*)(X + (size_t)n * 128 + lane * 2);
  float v0 = t2.x, v1 = t2.y;
  float s = wave_sum(v0 + v1);
  float s2 = wave_sum(v0 * v0 + v1 * v1);
  float mu = s * (1.f / 128);
  float var = fmaxf(s2 * (1.f / 128) - mu * mu, 0.f);
  float r = rsqrtf(var + 1e-5f);
  float g0 = g[lane * 2], g1v = g[lane * 2 + 1];
  float b0 = b[lane * 2], b1v = b[lane * 2 + 1];
  OT ov[2];
  ov[0] = (OT)fmaxf((v0 - mu) * r * g0 + b0, 0.f);
  ov[1] = (OT)fmaxf((v1 - mu) * r * g1v + b1v, 0.f);
  OT* op = Y + (size_t)n * ostride + lane * 2;
  __builtin_memcpy(op, ov, sizeof(ov));
}

// ---------------- CSR build (both ti fused) ----------------
__global__ void count2_kernel(const int* __restrict__ edge_index, int* __restrict__ deg) {
  int i = blockIdx.x * 256 + threadIdx.x;
  if (i >= 2 * EE) return;
  int ti = (i >= EE) ? 1 : 0;
  int e = i - ti * EE;
  int d = edge_index[(size_t)ti * 2 * EE + EE + e];
  atomicAdd(&deg[ti * NN + d], 1);
}

__global__ __launch_bounds__(1024) void scan2_kernel(
    const int* __restrict__ deg_all, int* __restrict__ rowptr_all,
    int* __restrict__ cursor_all) {
  const int ti = blockIdx.x;
  const int* deg = deg_all + ti * NN;
  int* rowptr = rowptr_all + ti * (NN + 1);
  int* cursor = cursor_all + ti * NN;
  __shared__ int sums[1024];
  int tid = threadIdx.x;
  int chunk = (NN + 1023) / 1024;
  int begin = tid * chunk, end = min(begin + chunk, NN);
  int s = 0;
  for (int i = begin; i < end; ++i) s += deg[i];
  sums[tid] = s;
  __syncthreads();
  for (int off = 1; off < 1024; off <<= 1) {
    int v = (tid >= off) ? sums[tid - off] : 0;
    __syncthreads();
    sums[tid] += v;
    __syncthreads();
  }
  int running = sums[tid] - s;  // exclusive prefix
  for (int i = begin; i < end; ++i) {
    rowptr[i] = running;
    cursor[i] = running;
    running += deg[i];
  }
  if (tid == 0) rowptr[NN] = EE;
}

__global__ void scatter2_kernel(const int* __restrict__ edge_index,
                                const float* __restrict__ edge_attr,
                                int* __restrict__ cursor_all,
                                Edge* __restrict__ edges_all) {
  int i = blockIdx.x * 256 + threadIdx.x;
  if (i >= 2 * EE) return;
  int ti = (i >= EE) ? 1 : 0;
  int e = i - ti * EE;
  const int* srcp = edge_index + (size_t)ti * 2 * EE;
  int s = srcp[e], d = srcp[EE + e];
  float2 ea = ((const float2*)edge_attr)[(size_t)ti * EE + e];
  int pos = atomicAdd(&cursor_all[ti * NN + d], 1);
  Edge ed;
  ed.src = s; ed.ea0 = (__bf16)ea.x; ed.ea1 = (__bf16)ea.y;
  __builtin_memcpy(&edges_all[(size_t)ti * EE + pos], &ed, sizeof(Edge));
}

// ---------------- GENConv softmax aggregation + residual (bf16 in/out) -----
__global__ __launch_bounds__(256) void agg_kernel(
    const __bf16* __restrict__ xin, const int* __restrict__ rowptr,
    const Edge* __restrict__ edges, const float* __restrict__ Wee,
    const float* __restrict__ bee, const float* __restrict__ tptr, int layer,
    __bf16* __restrict__ out, int nNodes) {
  int wave = threadIdx.x >> 6, lane = threadIdx.x & 63;
  int n = blockIdx.x * 4 + wave;
  if (n >= nNodes) return;
  float t = tptr[layer];
  int c0 = lane * 2;
  float w00 = Wee[c0], w01 = Wee[c0 + 1];
  float w10 = Wee[HH + c0], w11 = Wee[HH + c0 + 1];
  float be0 = bee[c0], be1 = bee[c0 + 1];
  float denA0 = 0.f, denA1 = 0.f, numA0 = 0.f, numA1 = 0.f;
  float denB0 = 0.f, denB1 = 0.f, numB0 = 0.f, numB1 = 0.f;
  int e = rowptr[n], e1 = rowptr[n + 1];

#define MLP(XV, ED, D0, D1, N0, N1)                                      \
  do {                                                                   \
    float eax = (float)(ED).ea0, eay = (float)(ED).ea1;                  \
    float m0 = (float)(XV)[0] + eax * w00 + eay * w10 + be0;             \
    float m1 = (float)(XV)[1] + eax * w01 + eay * w11 + be1;             \
    m0 = fmaxf(m0, 0.f) + EPS_MSG;                                       \
    m1 = fmaxf(m1, 0.f) + EPS_MSG;                                       \
    float ex0 = __expf(m0 * t), ex1 = __expf(m1 * t);                    \
    D0 += ex0; D1 += ex1; N0 += m0 * ex0; N1 += m1 * ex1;                \
  } while (0)

  for (; e + 4 <= e1; e += 4) {
    Edge E0 = edges[e], E1 = edges[e + 1], E2 = edges[e + 2], E3 = edges[e + 3];
    bf16x2 x0 = *(const bf16x2*)(xin + (size_t)E0.src * HH + c0);
    bf16x2 x1 = *(const bf16x2*)(xin + (size_t)E1.src * HH + c0);
    bf16x2 x2 = *(const bf16x2*)(xin + (size_t)E2.src * HH + c0);
    bf16x2 x3 = *(const bf16x2*)(xin + (size_t)E3.src * HH + c0);
    MLP(x0, E0, denA0, denA1, numA0, numA1);
    MLP(x1, E1, denB0, denB1, numB0, numB1);
    MLP(x2, E2, denA0, denA1, numA0, numA1);
    MLP(x3, E3, denB0, denB1, numB0, numB1);
  }
  for (; e < e1; ++e) {
    Edge E0 = edges[e];
    bf16x2 x0 = *(const bf16x2*)(xin + (size_t)E0.src * HH + c0);
    MLP(x0, E0, denA0, denA1, numA0, numA1);
  }
#undef MLP
  float den0 = denA0 + denB0, den1 = denA1 + denB1;
  float num0 = numA0 + numB0, num1 = numA1 + numB1;
  bf16x2 xr = *(const bf16x2*)(xin + (size_t)n * HH + c0);
  bf16x2 o;
  o[0] = (__bf16)(num0 / (den0 + 1e-16f) + (float)xr[0]);
  o[1] = (__bf16)(num1 / (den1 + 1e-16f) + (float)xr[1]);
  *(bf16x2*)(out + (size_t)n * HH + c0) = o;
}

// ---------------- channel attention over T=2 (wave per node) ----------------
template <typename OT>
__global__ __launch_bounds__(256) void attn_kernel(
    const float* __restrict__ emb, const float* __restrict__ Wq,
    const float* __restrict__ Wk, const float* __restrict__ Wv,
    const float* __restrict__ gammap, OT* __restrict__ out, int nNodes) {
  int wave = threadIdx.x >> 6, lane = threadIdx.x & 63;
  int n = blockIdx.x * 4 + wave;
  if (n >= nNodes) return;
  float gamma = *gammap;
  float wq00 = Wq[0], wq01 = Wq[1], wq10 = Wq[2], wq11 = Wq[3];
  float wk00 = Wk[0], wk01 = Wk[1], wk10 = Wk[2], wk11 = Wk[3];
  float wv00 = Wv[0], wv01 = Wv[1], wv10 = Wv[2], wv11 = Wv[3];
  int c0 = lane * 2;
  const float* base = emb + (size_t)n * (2 * HH);
  float2 x0 = *(const float2*)(base + c0);
  float2 x1 = *(const float2*)(base + HH + c0);
  float q0a = wq00 * x0.x + wq01 * x1.x, q0b = wq00 * x0.y + wq01 * x1.y;
  float q1a = wq10 * x0.x + wq11 * x1.x, q1b = wq10 * x0.y + wq11 * x1.y;
  float k0a = wk00 * x0.x + wk01 * x1.x, k0b = wk00 * x0.y + wk01 * x1.y;
  float k1a = wk10 * x0.x + wk11 * x1.x, k1b = wk10 * x0.y + wk11 * x1.y;
  float v0a = wv00 * x0.x + wv01 * x1.x, v0b = wv00 * x0.y + wv01 * x1.y;
  float v1a = wv10 * x0.x + wv11 * x1.x, v1b = wv10 * x0.y + wv11 * x1.y;
  float s00 = wave_sum(q0a * k0a + q0b * k0b);
  float s01 = wave_sum(q0a * k1a + q0b * k1b);
  float s10 = wave_sum(q1a * k0a + q1b * k0b);
  float s11 = wave_sum(q1a * k1a + q1b * k1b);
  float m0 = fmaxf(s00, s01);
  float e00 = __expf(s00 - m0), e01 = __expf(s01 - m0);
  float i0 = 1.f / (e00 + e01);
  float a00 = e00 * i0, a01 = e01 * i0;
  float m1 = fmaxf(s10, s11);
  float e10 = __expf(s10 - m1), e11 = __expf(s11 - m1);
  float i1 = 1.f / (e10 + e11);
  float a10 = e10 * i1, a11 = e11 * i1;
  OT* op = out + (size_t)n * (2 * HH);
  op[c0] = (OT)(gamma * (a00 * v0a + a01 * v1a) + x0.x);
  op[c0 + 1] = (OT)(gamma * (a00 * v0b + a01 * v1b) + x0.y);
  op[HH + c0] = (OT)(gamma * (a10 * v0a + a11 * v1a) + x1.x);
  op[HH + c0 + 1] = (OT)(gamma * (a10 * v0b + a11 * v1b) + x1.y);
}

// ---------------- mean pool ----------------
__global__ __launch_bounds__(256) void pool_kernel(const float* __restrict__ gbuf,
                                                   float* __restrict__ gp_sum, int nNodes) {
  int c = threadIdx.x;
  float s = 0.f;
  for (int r = blockIdx.x; r < nNodes; r += gridDim.x) s += gbuf[(size_t)r * 256 + c];
  atomicAdd(&gp_sum[c], s);
}

// ---------------- graph head (single block) ----------------
__global__ __launch_bounds__(256) void graph_head_kernel(
    const float* __restrict__ gp_sum, const float* __restrict__ Wg1,
    const float* __restrict__ bg1, const float* __restrict__ Wg2,
    const float* __restrict__ bg2, float* __restrict__ outp, float invN) {
  __shared__ float gp[256];
  __shared__ float h1[256];
  __shared__ float lg[2];
  int tid = threadIdx.x;
  gp[tid] = gp_sum[tid] * invN;
  __syncthreads();
  float acc = bg1[tid];
  for (int k = 0; k < 256; ++k) acc += gp[k] * Wg1[k * 256 + tid];
  h1[tid] = fmaxf(acc, 0.f);
  __syncthreads();
  if (tid < 2) {
    float l = bg2[tid];
    for (int c = 0; c < 256; ++c) l += h1[c] * Wg2[c * 2 + tid];
    lg[tid] = l;
  }
  __syncthreads();
  if (tid == 0) {
    float m = fmaxf(lg[0], lg[1]);
    float lse = m + logf(__expf(lg[0] - m) + __expf(lg[1] - m));
    outp[0] = lg[0] - lse;
    outp[1] = lg[1] - lse;
  }
}

// ---------------- launch ----------------
extern "C" void kernel_launch(void* const* d_in, const int* in_sizes, int n_in,
                              void* d_out, int out_size, void* d_ws, size_t ws_size,
                              hipStream_t stream) {
  (void)in_sizes; (void)n_in; (void)out_size; (void)ws_size;
  const float* node_feature = (const float*)d_in[0];
  const int* edge_index = (const int*)d_in[1];
  const float* edge_attr = (const float*)d_in[2];
  const float* Wne = (const float*)d_in[3];
  const float* bne = (const float*)d_in[4];
  const float* Wee = (const float*)d_in[5];
  const float* bee = (const float*)d_in[6];
  const float* W1 = (const float*)d_in[7];
  const float* b1 = (const float*)d_in[8];
  const float* g1 = (const float*)d_in[9];
  const float* be1 = (const float*)d_in[10];
  const float* W2 = (const float*)d_in[11];
  const float* b2 = (const float*)d_in[12];
  const float* dg = (const float*)d_in[13];
  const float* db = (const float*)d_in[14];
  const float* tpar = (const float*)d_in[15];
  const float* Wq_n = (const float*)d_in[16];
  const float* Wk_n = (const float*)d_in[17];
  const float* Wv_n = (const float*)d_in[18];
  const float* gamma_n = (const float*)d_in[19];
  const float* Wn1 = (const float*)d_in[20];
  const float* bn1 = (const float*)d_in[21];
  const float* Wn2 = (const float*)d_in[22];
  const float* bn2 = (const float*)d_in[23];
  const float* Wq_g = (const float*)d_in[24];
  const float* Wk_g = (const float*)d_in[25];
  const float* Wv_g = (const float*)d_in[26];
  const float* gamma_g = (const float*)d_in[27];
  const float* Wg1 = (const float*)d_in[28];
  const float* bg1 = (const float*)d_in[29];
  const float* Wg2 = (const float*)d_in[30];
  const float* bg2 = (const float*)d_in[31];
  float* out = (float*)d_out;

  // ---- workspace carve-out (256B-aligned regions) ----
  char* pc = (char*)d_ws;
  auto alloc = [&](size_t bytes) {
    char* r = pc;
    pc += (bytes + 255) & ~(size_t)255;
    return r;
  };
  float* xbuf = (float*)alloc((size_t)NN * HH * 4);        // f32 residual chain
  __bf16* hbuf_b = (__bf16*)alloc((size_t)MP * HH * 2);    // LN'd agg input
  float* emb = (float*)alloc((size_t)NN * 2 * HH * 4);     // [N,T,H] f32
  __bf16* aggout_b = (__bf16*)alloc((size_t)MP * HH * 2);  // agg out (nf spill)
  __bf16* nf_b = (__bf16*)emb;  // 20096*576*2=23.2MB <= emb(20.48)+aggout(5.15)
  __bf16* t256_b = (__bf16*)alloc((size_t)MP * 2 * HH * 2);  // LN'd lin1 out
  __bf16* attnb = t256_b;       // alias: node-attn bf16 out (after last lin2)
  float* buf2 = (float*)alloc((size_t)NN * 2 * HH * 4);      // graph-attn out
  __bf16* x_enc_b = (__bf16*)alloc((size_t)MP * HH * 2);
  __bf16* wt_ne = (__bf16*)alloc((size_t)128 * 576 * 2);
  __bf16* wt1 = (__bf16*)alloc((size_t)4 * 256 * 128 * 2);
  __bf16* wt2 = (__bf16*)alloc((size_t)4 * 128 * 256 * 2);
  __bf16* wtn1 = (__bf16*)alloc((size_t)256 * 256 * 2);
  float* gp_sum = (float*)alloc(256 * 4);
  int* deg = (int*)alloc((size_t)2 * NN * 4);
  int* cursor = (int*)alloc((size_t)2 * NN * 4);
  int* rowptr = (int*)alloc((size_t)2 * (NN + 1) * 4 + 8);
  Edge* edges = (Edge*)alloc((size_t)2 * EE * 8);

  const int rows4 = (NN + 3) / 4;
  const dim3 gN128(1, MP / 64);  // generic gemm: 314 blocks, N=128
  const int g256 = MP / 64;      // gemm256: 314 blocks

  // 0. conversions
  nf_convert_kernel<<<(NN * 576 + 255) / 256, 256, 0, stream>>>(node_feature, nf_b);
  WtDescs wd;
  wd.d[0] = {Wne, wt_ne, FF, HH, 576};
  for (int l = 0; l < 4; ++l)
    wd.d[1 + l] = {W1 + (size_t)l * HH * 256, wt1 + (size_t)l * 256 * HH, HH, 256, HH};
  for (int l = 0; l < 4; ++l)
    wd.d[5 + l] = {W2 + (size_t)l * 256 * HH, wt2 + (size_t)l * HH * 256, 256, HH, 256};
  wd.d[9] = {Wn1, wtn1, 256, 256, 256};
  wt_convert_kernel<<<dim3((128 * 576 + 255) / 256, 10), 256, 0, stream>>>(wd);

  // CSR for both ti
  hipMemsetAsync(deg, 0, 2 * NN * sizeof(int), stream);
  count2_kernel<<<(2 * EE + 255) / 256, 256, 0, stream>>>(edge_index, deg);
  scan2_kernel<<<2, 1024, 0, stream>>>(deg, rowptr, cursor);
  scatter2_kernel<<<(2 * EE + 255) / 256, 256, 0, stream>>>(edge_index, edge_attr,
                                                            cursor, edges);

  // 1. node encoder (ti-independent): x_enc_b = bf16(nf @ Wne + bne)
  gemm_mfma<false, false, __bf16><<<gN128, 256, 0, stream>>>(nf_b, wt_ne, bne, nullptr,
                                                             x_enc_b, NN, HH, 576);

  for (int ti = 0; ti < TT; ++ti) {
    const int* rp = rowptr + ti * (NN + 1);
    const Edge* ed = edges + (size_t)ti * EE;

    for (int l = 0; l < LL; ++l) {
      const __bf16* gin;
      if (l == 0) {
        gin = x_enc_b;
      } else {
        lnrelu128_kernel<__bf16><<<rows4, 256, 0, stream>>>(
            xbuf, dg + l * HH, db + l * HH, hbuf_b, NN, HH);
        gin = hbuf_b;
      }
      agg_kernel<<<rows4, 256, 0, stream>>>(gin, rp, ed, Wee, bee, tpar, l, aggout_b,
                                            NN);
      // lin1 + bias + LN + relu -> bf16, fused
      gemm256<0><<<g256, 256, 0, stream>>>(aggout_b, wt1 + (size_t)l * 256 * HH,
                                           b1 + l * 2 * HH, g1 + l * 2 * HH,
                                           be1 + l * 2 * HH, nullptr, nullptr, t256_b,
                                           NN, HH);
      if (l == 0)
        gemm_mfma<false, false, float><<<gN128, 256, 0, stream>>>(
            t256_b, wt2 + (size_t)l * HH * 256, b2 + l * HH, nullptr, xbuf, NN, HH,
            256);
      else
        gemm_mfma<false, true, float><<<gN128, 256, 0, stream>>>(
            t256_b, wt2 + (size_t)l * HH * 256, b2 + l * HH, xbuf, xbuf, NN, HH, 256);
    }
    // final relu(LN(x; dg[0], db[0])) -> emb[:, ti, :]
    lnrelu128_kernel<float><<<rows4, 256, 0, stream>>>(xbuf, dg, db, emb + ti * HH, NN,
                                                       2 * HH);
  }

  // node branch: attn -> [lin1+relu+Wn2+log_softmax] fused
  attn_kernel<__bf16><<<rows4, 256, 0, stream>>>(emb, Wq_n, Wk_n, Wv_n, gamma_n,
                                                 attnb, NN);
  gemm256<1><<<g256, 256, 0, stream>>>(attnb, wtn1, bn1, nullptr, nullptr, Wn2, bn2,
                                       out, NN, 256);

  // graph branch
  attn_kernel<float><<<rows4, 256, 0, stream>>>(emb, Wq_g, Wk_g, Wv_g, gamma_g, buf2,
                                                NN);
  hipMemsetAsync(gp_sum, 0, 256 * sizeof(float), stream);
  pool_kernel<<<128, 256, 0, stream>>>(buf2, gp_sum, NN);
  graph_head_kernel<<<1, 256, 0, stream>>>(gp_sum, Wg1, bg1, Wg2, bg2,
                                           out + (size_t)NN * CN, 1.0f / NN);
}

// Round 5
// 512.854 us; speedup vs baseline: 3.1902x; 1.2556x over previous
//
#include <hip/hip_runtime.h>

#define NN 20000
#define TT 2
#define HH 128
#define LL 4
#define EE 320000
#define FF 514
#define CN 3
#define CG 2
#define EPS_MSG 1e-7f
#define MP 20096  // rows per ti-half, padded to multiple of 128

typedef __bf16 bf16x8 __attribute__((ext_vector_type(8)));
typedef __bf16 bf16x2 __attribute__((ext_vector_type(2)));
typedef float f32x4 __attribute__((ext_vector_type(4)));

struct __align__(8) Edge { int src; __bf16 ea0, ea1; };

// ---------------- wave helpers ----------------
__device__ inline float wave_sum(float v) {
#pragma unroll
  for (int off = 32; off; off >>= 1) v += __shfl_xor(v, off);
  return v;
}
__device__ inline float red16(float v) {  // reduce across fr = lane&15
  v += __shfl_xor(v, 1); v += __shfl_xor(v, 2);
  v += __shfl_xor(v, 4); v += __shfl_xor(v, 8);
  return v;
}

__device__ __forceinline__ void gload_lds16(const void* g, void* l) {
  __builtin_amdgcn_global_load_lds(
      (const __attribute__((address_space(1))) unsigned int*)g,
      (__attribute__((address_space(3))) unsigned int*)l, 16, 0, 0);
}

// ---------------- generic bf16 MFMA GEMM (BM=64,BN=128,BK=32, dbuf) --------
// C = A[M,K]@BT[N,K]^T + bias. Optional dupRows: also store at row gm+dupRows.
template <typename OT>
__global__ __launch_bounds__(256) void gemm_mfma(
    const __bf16* __restrict__ A, const __bf16* __restrict__ BT,
    const float* __restrict__ bias, OT* __restrict__ C, int M, int N, int K,
    int dupRows) {
  __shared__ __bf16 As[2][64][32];
  __shared__ __bf16 Bs[2][128][32];
  const int tid = threadIdx.x;
  const int lane = tid & 63, w = tid >> 6;
  const int bm = blockIdx.y * 64, bn = blockIdx.x * 128;
  const int wr = (w >> 1) * 32, wc = (w & 1) * 64;
  const int fr = lane & 15, fq = lane >> 4;
  const int rowA = tid >> 2, chA = (tid & 3) * 8;
  const __bf16* Ab = A + (size_t)(bm + rowA) * K + chA;
  const __bf16* Bb = BT + (size_t)(bn + rowA) * K + chA;
  const __bf16* Bb2 = Bb + (size_t)64 * K;
  f32x4 acc[2][4] = {};

#define STAGE(buf, k0)                                  \
  do {                                                  \
    gload_lds16(Ab + (k0), &As[buf][rowA][chA]);        \
    gload_lds16(Bb + (k0), &Bs[buf][rowA][chA]);        \
    gload_lds16(Bb2 + (k0), &Bs[buf][rowA + 64][chA]);  \
  } while (0)

  STAGE(0, 0);
  __syncthreads();
  int cur = 0;
  for (int k0 = 0; k0 < K; k0 += 32) {
    if (k0 + 32 < K) STAGE(cur ^ 1, k0 + 32);
    bf16x8 af[2], bq[4];
#pragma unroll
    for (int m = 0; m < 2; ++m)
      af[m] = *(const bf16x8*)&As[cur][wr + m * 16 + fr][fq * 8];
#pragma unroll
    for (int n = 0; n < 4; ++n)
      bq[n] = *(const bf16x8*)&Bs[cur][wc + n * 16 + fr][fq * 8];
#pragma unroll
    for (int m = 0; m < 2; ++m)
#pragma unroll
      for (int n = 0; n < 4; ++n)
        acc[m][n] =
            __builtin_amdgcn_mfma_f32_16x16x32_bf16(af[m], bq[n], acc[m][n], 0, 0, 0);
    __syncthreads();
    cur ^= 1;
  }
#undef STAGE

#pragma unroll
  for (int m = 0; m < 2; ++m) {
#pragma unroll
    for (int n = 0; n < 4; ++n) {
#pragma unroll
      for (int j = 0; j < 4; ++j) {
        int gm = bm + wr + m * 16 + fq * 4 + j;
        int gn = bn + wc + n * 16 + fr;
        if (gm < M) {
          float c = acc[m][n][j] + bias[gn];
          C[(size_t)gm * N + gn] = (OT)c;
          if (dupRows) C[(size_t)(gm + dupRows) * N + gn] = (OT)c;
        }
      }
    }
  }
}

// ---------------- fused 256-wide GEMM (BM=64, BN=256, full row per wave) ----
// EPI 0: LN(c; g,be) -> relu -> bf16 out [rows][256]
// EPI 1: relu(c) -> @W2h[256,3] + b2h -> log_softmax -> f32 out [M][3]
template <int EPI>
__global__ __launch_bounds__(256) void gemm256(
    const __bf16* __restrict__ A, const __bf16* __restrict__ BT,
    const float* __restrict__ bias, const float* __restrict__ g,
    const float* __restrict__ be, const float* __restrict__ W2h,
    const float* __restrict__ b2h, void* __restrict__ outp, int M, int K) {
  __shared__ __bf16 As[2][64][32];
  __shared__ __bf16 Bs[2][256][32];
  const int tid = threadIdx.x;
  const int lane = tid & 63, w = tid >> 6;
  const int bm = blockIdx.x * 64;
  const int wr = w * 16;
  const int fr = lane & 15, fq = lane >> 4;
  const int rowA = tid >> 2, chA = (tid & 3) * 8;
  const __bf16* Ab = A + (size_t)(bm + rowA) * K + chA;
  const __bf16* Bb = BT + (size_t)rowA * K + chA;
  f32x4 acc[16] = {};

#define STG(buf, k0)                                                \
  do {                                                              \
    gload_lds16(Ab + (k0), &As[buf][rowA][chA]);                    \
    _Pragma("unroll") for (int r = 0; r < 4; ++r)                   \
        gload_lds16(Bb + (size_t)(r * 64) * K + (k0),               \
                    &Bs[buf][rowA + r * 64][chA]);                  \
  } while (0)

  STG(0, 0);
  __syncthreads();
  int cur = 0;
  for (int k0 = 0; k0 < K; k0 += 32) {
    if (k0 + 32 < K) STG(cur ^ 1, k0 + 32);
    bf16x8 af = *(const bf16x8*)&As[cur][wr + fr][fq * 8];
#pragma unroll
    for (int n = 0; n < 16; ++n) {
      bf16x8 bq = *(const bf16x8*)&Bs[cur][n * 16 + fr][fq * 8];
      acc[n] = __builtin_amdgcn_mfma_f32_16x16x32_bf16(af, bq, acc[n], 0, 0, 0);
    }
    __syncthreads();
    cur ^= 1;
  }
#undef STG

  float cb[16];
#pragma unroll
  for (int n = 0; n < 16; ++n) cb[n] = bias[n * 16 + fr];

  if constexpr (EPI == 0) {
    float gv[16], bev[16];
#pragma unroll
    for (int n = 0; n < 16; ++n) {
      gv[n] = g[n * 16 + fr];
      bev[n] = be[n * 16 + fr];
    }
    __bf16* outb = (__bf16*)outp;
#pragma unroll
    for (int j = 0; j < 4; ++j) {
      float cj[16], s = 0.f, s2 = 0.f;
#pragma unroll
      for (int n = 0; n < 16; ++n) {
        float c = acc[n][j] + cb[n];
        cj[n] = c; s += c; s2 += c * c;
      }
      s = red16(s); s2 = red16(s2);
      float mu = s * (1.f / 256);
      float var = fmaxf(s2 * (1.f / 256) - mu * mu, 0.f);
      float rr = rsqrtf(var + 1e-5f);
      int gm = bm + wr + fq * 4 + j;
      __bf16* op = outb + (size_t)gm * 256;
#pragma unroll
      for (int n = 0; n < 16; ++n) {
        float y = (cj[n] - mu) * rr * gv[n] + bev[n];
        op[n * 16 + fr] = (__bf16)fmaxf(y, 0.f);
      }
    }
  } else {
    float w0[16], w1[16], w2[16];
#pragma unroll
    for (int n = 0; n < 16; ++n) {
      int col = n * 16 + fr;
      w0[n] = W2h[col * 3 + 0];
      w1[n] = W2h[col * 3 + 1];
      w2[n] = W2h[col * 3 + 2];
    }
    float* outf = (float*)outp;
#pragma unroll
    for (int j = 0; j < 4; ++j) {
      float p0 = 0.f, p1 = 0.f, p2 = 0.f;
#pragma unroll
      for (int n = 0; n < 16; ++n) {
        float h = fmaxf(acc[n][j] + cb[n], 0.f);
        p0 += h * w0[n]; p1 += h * w1[n]; p2 += h * w2[n];
      }
      p0 = red16(p0); p1 = red16(p1); p2 = red16(p2);
      int gm = bm + wr + fq * 4 + j;
      if (fr == 0 && gm < M) {
        float l0 = p0 + b2h[0], l1 = p1 + b2h[1], l2 = p2 + b2h[2];
        float m = fmaxf(l0, fmaxf(l1, l2));
        float lse = m + logf(__expf(l0 - m) + __expf(l1 - m) + __expf(l2 - m));
        outf[(size_t)gm * 3 + 0] = l0 - lse;
        outf[(size_t)gm * 3 + 1] = l1 - lse;
        outf[(size_t)gm * 3 + 2] = l2 - lse;
      }
    }
  }
}

// ---------------- lin2 GEMM + residual + fused LayerNorm+ReLU --------------
// A[rows][256] @ BT[128][256]^T + bias (+xres). BN=128 = full row per block.
// MODE 0: write xres (no add) + LN->relu->bf16 hb      (layer 0)
// MODE 1: add xres, write xres + LN->relu->bf16 hb     (layers 1..L-2)
// MODE 2: add xres, LN->relu->f32 emb[node*256+half*128+col] (last layer)
template <int MODE>
__global__ __launch_bounds__(256) void gemm_lin2(
    const __bf16* __restrict__ A, const __bf16* __restrict__ BT,
    const float* __restrict__ bias, float* __restrict__ xres,
    const float* __restrict__ g, const float* __restrict__ be,
    void* __restrict__ lnout) {
  __shared__ __bf16 As[2][64][32];
  __shared__ __bf16 Bs[2][128][32];
  __shared__ float redS[64][2], redS2[64][2];
  const int tid = threadIdx.x;
  const int lane = tid & 63, w = tid >> 6;
  const int bm = blockIdx.x * 64;
  const int wr = (w >> 1) * 32, wc = (w & 1) * 64;
  const int fr = lane & 15, fq = lane >> 4;
  const int rowA = tid >> 2, chA = (tid & 3) * 8;
  const __bf16* Ab = A + (size_t)(bm + rowA) * 256 + chA;
  const __bf16* Bb = BT + (size_t)rowA * 256 + chA;
  const __bf16* Bb2 = Bb + (size_t)64 * 256;
  f32x4 acc[2][4] = {};

#define STAGE(buf, k0)                                  \
  do {                                                  \
    gload_lds16(Ab + (k0), &As[buf][rowA][chA]);        \
    gload_lds16(Bb + (k0), &Bs[buf][rowA][chA]);        \
    gload_lds16(Bb2 + (k0), &Bs[buf][rowA + 64][chA]);  \
  } while (0)

  STAGE(0, 0);
  __syncthreads();
  int cur = 0;
  for (int k0 = 0; k0 < 256; k0 += 32) {
    if (k0 + 32 < 256) STAGE(cur ^ 1, k0 + 32);
    bf16x8 af[2], bq[4];
#pragma unroll
    for (int m = 0; m < 2; ++m)
      af[m] = *(const bf16x8*)&As[cur][wr + m * 16 + fr][fq * 8];
#pragma unroll
    for (int n = 0; n < 4; ++n)
      bq[n] = *(const bf16x8*)&Bs[cur][wc + n * 16 + fr][fq * 8];
#pragma unroll
    for (int m = 0; m < 2; ++m)
#pragma unroll
      for (int n = 0; n < 4; ++n)
        acc[m][n] =
            __builtin_amdgcn_mfma_f32_16x16x32_bf16(af[m], bq[n], acc[m][n], 0, 0, 0);
    __syncthreads();
    cur ^= 1;
  }
#undef STAGE

  // epilogue: c = acc + bias (+ xres); per-row LN over 128 cols (2 wave-halves)
  float cv[2][4][4];
#pragma unroll
  for (int m = 0; m < 2; ++m) {
    int r0 = wr + m * 16 + fq * 4;
#pragma unroll
    for (int j = 0; j < 4; ++j) {
      int gm = bm + r0 + j;
      float s = 0.f, s2 = 0.f;
#pragma unroll
      for (int n = 0; n < 4; ++n) {
        float c = acc[m][n][j] + bias[wc + n * 16 + fr];
        if (MODE != 0) c += xres[(size_t)gm * 128 + wc + n * 16 + fr];
        cv[m][n][j] = c;
        s += c; s2 += c * c;
      }
      s = red16(s); s2 = red16(s2);
      if (fr == 0) {
        redS[r0 + j][w & 1] = s;
        redS2[r0 + j][w & 1] = s2;
      }
    }
  }
  __syncthreads();
#pragma unroll
  for (int m = 0; m < 2; ++m) {
    int r0 = wr + m * 16 + fq * 4;
#pragma unroll
    for (int j = 0; j < 4; ++j) {
      int r = r0 + j;
      int gm = bm + r;
      float S = redS[r][0] + redS[r][1];
      float S2 = redS2[r][0] + redS2[r][1];
      float mu = S * (1.f / 128);
      float var = fmaxf(S2 * (1.f / 128) - mu * mu, 0.f);
      float rr = rsqrtf(var + 1e-5f);
      if constexpr (MODE < 2) {
        float* xp = xres + (size_t)gm * 128;
        __bf16* hp = (__bf16*)lnout + (size_t)gm * 128;
#pragma unroll
        for (int n = 0; n < 4; ++n) {
          int col = wc + n * 16 + fr;
          float c = cv[m][n][j];
          xp[col] = c;
          float y = (c - mu) * rr * g[col] + be[col];
          hp[col] = (__bf16)fmaxf(y, 0.f);
        }
      } else {
        int half = gm >= MP;
        int node = gm - half * MP;
        if (node < NN) {
          float* ep = (float*)lnout + (size_t)node * 256 + half * 128;
#pragma unroll
          for (int n = 0; n < 4; ++n) {
            int col = wc + n * 16 + fr;
            float y = (cv[m][n][j] - mu) * rr * g[col] + be[col];
            ep[col] = fmaxf(y, 0.f);
          }
        }
      }
    }
  }
}

// ---------------- conversions ----------------
__global__ void nf_convert_kernel(const float* __restrict__ src, __bf16* __restrict__ dst) {
  int idx = blockIdx.x * 256 + threadIdx.x;
  if (idx >= NN * 576) return;
  int row = idx / 576, col = idx - row * 576;
  float v = (col < FF) ? src[(size_t)row * FF + col] : 0.f;
  dst[idx] = (__bf16)v;
}

struct WtDesc { const float* src; __bf16* dst; int K, N, Kpad; };
struct WtDescs { WtDesc d[10]; };

__global__ void wt_convert_kernel(WtDescs descs) {
  WtDesc de = descs.d[blockIdx.y];
  int idx = blockIdx.x * 256 + threadIdx.x;
  if (idx >= de.N * de.Kpad) return;
  int n = idx / de.Kpad, k = idx - n * de.Kpad;
  float v = (k < de.K) ? de.src[(size_t)k * de.N + n] : 0.f;
  de.dst[idx] = (__bf16)v;
}

// ---------------- CSR build (both ti, unified rowptr) ----------------
__global__ void count2_kernel(const int* __restrict__ edge_index, int* __restrict__ deg) {
  int i = blockIdx.x * 256 + threadIdx.x;
  if (i >= 2 * EE) return;
  int ti = (i >= EE) ? 1 : 0;
  int e = i - ti * EE;
  int d = edge_index[(size_t)ti * 2 * EE + EE + e];
  atomicAdd(&deg[ti * NN + d], 1);
}

__global__ __launch_bounds__(1024) void scan2_kernel(
    const int* __restrict__ deg_all, int* __restrict__ rowptr,
    int* __restrict__ cursor) {
  const int ti = blockIdx.x;
  const int* deg = deg_all + ti * NN;
  __shared__ int sums[1024];
  int tid = threadIdx.x;
  int chunk = (NN + 1023) / 1024;
  int begin = tid * chunk, end = min(begin + chunk, NN);
  int s = 0;
  for (int i = begin; i < end; ++i) s += deg[i];
  sums[tid] = s;
  __syncthreads();
  for (int off = 1; off < 1024; off <<= 1) {
    int v = (tid >= off) ? sums[tid - off] : 0;
    __syncthreads();
    sums[tid] += v;
    __syncthreads();
  }
  int running = ti * EE + sums[tid] - s;  // exclusive prefix + ti base
  for (int i = begin; i < end; ++i) {
    rowptr[ti * NN + i] = running;
    cursor[ti * NN + i] = running;
    running += deg[i];
  }
  if (tid == 0 && ti == 1) rowptr[2 * NN] = 2 * EE;
}

__global__ void scatter2_kernel(const int* __restrict__ edge_index,
                                const float* __restrict__ edge_attr,
                                int* __restrict__ cursor,
                                Edge* __restrict__ edges) {
  int i = blockIdx.x * 256 + threadIdx.x;
  if (i >= 2 * EE) return;
  int ti = (i >= EE) ? 1 : 0;
  int e = i - ti * EE;
  const int* srcp = edge_index + (size_t)ti * 2 * EE;
  int s = srcp[e], d = srcp[EE + e];
  float2 ea = ((const float2*)edge_attr)[(size_t)ti * EE + e];
  int pos = atomicAdd(&cursor[ti * NN + d], 1);
  Edge ed;
  ed.src = s + ti * MP;  // absolute row in stacked x
  ed.ea0 = (__bf16)ea.x; ed.ea1 = (__bf16)ea.y;
  __builtin_memcpy(&edges[pos], &ed, sizeof(Edge));
}

// ---------------- GENConv softmax aggregation + residual (stacked halves) --
__global__ __launch_bounds__(256) void agg_kernel(
    const __bf16* __restrict__ xin, const int* __restrict__ rowptr,
    const Edge* __restrict__ edges, const float* __restrict__ Wee,
    const float* __restrict__ bee, const float* __restrict__ tptr, int layer,
    __bf16* __restrict__ out) {
  int wave = threadIdx.x >> 6, lane = threadIdx.x & 63;
  int gnode = blockIdx.x * 4 + wave;
  if (gnode >= 2 * NN) return;
  int half = gnode >= NN;
  int xrow = half ? (gnode - NN + MP) : gnode;  // stacked memory row
  float t = tptr[layer];
  int c0 = lane * 2;
  float w00 = Wee[c0], w01 = Wee[c0 + 1];
  float w10 = Wee[HH + c0], w11 = Wee[HH + c0 + 1];
  float be0 = bee[c0], be1 = bee[c0 + 1];
  float denA0 = 0.f, denA1 = 0.f, numA0 = 0.f, numA1 = 0.f;
  float denB0 = 0.f, denB1 = 0.f, numB0 = 0.f, numB1 = 0.f;
  int e = rowptr[gnode], e1 = rowptr[gnode + 1];

#define MLP(XV, ED, D0, D1, N0, N1)                                      \
  do {                                                                   \
    float eax = (float)(ED).ea0, eay = (float)(ED).ea1;                  \
    float m0 = (float)(XV)[0] + eax * w00 + eay * w10 + be0;             \
    float m1 = (float)(XV)[1] + eax * w01 + eay * w11 + be1;             \
    m0 = fmaxf(m0, 0.f) + EPS_MSG;                                       \
    m1 = fmaxf(m1, 0.f) + EPS_MSG;                                       \
    float ex0 = __expf(m0 * t), ex1 = __expf(m1 * t);                    \
    D0 += ex0; D1 += ex1; N0 += m0 * ex0; N1 += m1 * ex1;                \
  } while (0)

  for (; e + 4 <= e1; e += 4) {
    Edge E0 = edges[e], E1 = edges[e + 1], E2 = edges[e + 2], E3 = edges[e + 3];
    bf16x2 x0 = *(const bf16x2*)(xin + (size_t)E0.src * HH + c0);
    bf16x2 x1 = *(const bf16x2*)(xin + (size_t)E1.src * HH + c0);
    bf16x2 x2 = *(const bf16x2*)(xin + (size_t)E2.src * HH + c0);
    bf16x2 x3 = *(const bf16x2*)(xin + (size_t)E3.src * HH + c0);
    MLP(x0, E0, denA0, denA1, numA0, numA1);
    MLP(x1, E1, denB0, denB1, numB0, numB1);
    MLP(x2, E2, denA0, denA1, numA0, numA1);
    MLP(x3, E3, denB0, denB1, numB0, numB1);
  }
  for (; e < e1; ++e) {
    Edge E0 = edges[e];
    bf16x2 x0 = *(const bf16x2*)(xin + (size_t)E0.src * HH + c0);
    MLP(x0, E0, denA0, denA1, numA0, numA1);
  }
#undef MLP
  float den0 = denA0 + denB0, den1 = denA1 + denB1;
  float num0 = numA0 + numB0, num1 = numA1 + numB1;
  bf16x2 xr = *(const bf16x2*)(xin + (size_t)xrow * HH + c0);
  bf16x2 o;
  o[0] = (__bf16)(num0 / (den0 + 1e-16f) + (float)xr[0]);
  o[1] = (__bf16)(num1 / (den1 + 1e-16f) + (float)xr[1]);
  *(bf16x2*)(out + (size_t)xrow * HH + c0) = o;
}

// ---------------- channel attention over T=2 (wave per node) ----------------
template <typename OT>
__global__ __launch_bounds__(256) void attn_kernel(
    const float* __restrict__ emb, const float* __restrict__ Wq,
    const float* __restrict__ Wk, const float* __restrict__ Wv,
    const float* __restrict__ gammap, OT* __restrict__ out, int nNodes) {
  int wave = threadIdx.x >> 6, lane = threadIdx.x & 63;
  int n = blockIdx.x * 4 + wave;
  if (n >= nNodes) return;
  float gamma = *gammap;
  float wq00 = Wq[0], wq01 = Wq[1], wq10 = Wq[2], wq11 = Wq[3];
  float wk00 = Wk[0], wk01 = Wk[1], wk10 = Wk[2], wk11 = Wk[3];
  float wv00 = Wv[0], wv01 = Wv[1], wv10 = Wv[2], wv11 = Wv[3];
  int c0 = lane * 2;
  const float* base = emb + (size_t)n * (2 * HH);
  float2 x0 = *(const float2*)(base + c0);
  float2 x1 = *(const float2*)(base + HH + c0);
  float q0a = wq00 * x0.x + wq01 * x1.x, q0b = wq00 * x0.y + wq01 * x1.y;
  float q1a = wq10 * x0.x + wq11 * x1.x, q1b = wq10 * x0.y + wq11 * x1.y;
  float k0a = wk00 * x0.x + wk01 * x1.x, k0b = wk00 * x0.y + wk01 * x1.y;
  float k1a = wk10 * x0.x + wk11 * x1.x, k1b = wk10 * x0.y + wk11 * x1.y;
  float v0a = wv00 * x0.x + wv01 * x1.x, v0b = wv00 * x0.y + wv01 * x1.y;
  float v1a = wv10 * x0.x + wv11 * x1.x, v1b = wv10 * x0.y + wv11 * x1.y;
  float s00 = wave_sum(q0a * k0a + q0b * k0b);
  float s01 = wave_sum(q0a * k1a + q0b * k1b);
  float s10 = wave_sum(q1a * k0a + q1b * k0b);
  float s11 = wave_sum(q1a * k1a + q1b * k1b);
  float m0 = fmaxf(s00, s01);
  float e00 = __expf(s00 - m0), e01 = __expf(s01 - m0);
  float i0 = 1.f / (e00 + e01);
  float a00 = e00 * i0, a01 = e01 * i0;
  float m1 = fmaxf(s10, s11);
  float e10 = __expf(s10 - m1), e11 = __expf(s11 - m1);
  float i1 = 1.f / (e10 + e11);
  float a10 = e10 * i1, a11 = e11 * i1;
  OT* op = out + (size_t)n * (2 * HH);
  op[c0] = (OT)(gamma * (a00 * v0a + a01 * v1a) + x0.x);
  op[c0 + 1] = (OT)(gamma * (a00 * v0b + a01 * v1b) + x0.y);
  op[HH + c0] = (OT)(gamma * (a10 * v0a + a11 * v1a) + x1.x);
  op[HH + c0 + 1] = (OT)(gamma * (a10 * v0b + a11 * v1b) + x1.y);
}

// ---------------- mean pool ----------------
__global__ __launch_bounds__(256) void pool_kernel(const float* __restrict__ gbuf,
                                                   float* __restrict__ gp_sum, int nNodes) {
  int c = threadIdx.x;
  float s = 0.f;
  for (int r = blockIdx.x; r < nNodes; r += gridDim.x) s += gbuf[(size_t)r * 256 + c];
  atomicAdd(&gp_sum[c], s);
}

// ---------------- graph head (single block) ----------------
__global__ __launch_bounds__(256) void graph_head_kernel(
    const float* __restrict__ gp_sum, const float* __restrict__ Wg1,
    const float* __restrict__ bg1, const float* __restrict__ Wg2,
    const float* __restrict__ bg2, float* __restrict__ outp, float invN) {
  __shared__ float gp[256];
  __shared__ float h1[256];
  __shared__ float lg[2];
  int tid = threadIdx.x;
  gp[tid] = gp_sum[tid] * invN;
  __syncthreads();
  float acc = bg1[tid];
  for (int k = 0; k < 256; ++k) acc += gp[k] * Wg1[k * 256 + tid];
  h1[tid] = fmaxf(acc, 0.f);
  __syncthreads();
  if (tid < 2) {
    float l = bg2[tid];
    for (int c = 0; c < 256; ++c) l += h1[c] * Wg2[c * 2 + tid];
    lg[tid] = l;
  }
  __syncthreads();
  if (tid == 0) {
    float m = fmaxf(lg[0], lg[1]);
    float lse = m + logf(__expf(lg[0] - m) + __expf(lg[1] - m));
    outp[0] = lg[0] - lse;
    outp[1] = lg[1] - lse;
  }
}

// ---------------- launch ----------------
extern "C" void kernel_launch(void* const* d_in, const int* in_sizes, int n_in,
                              void* d_out, int out_size, void* d_ws, size_t ws_size,
                              hipStream_t stream) {
  (void)in_sizes; (void)n_in; (void)out_size; (void)ws_size;
  const float* node_feature = (const float*)d_in[0];
  const int* edge_index = (const int*)d_in[1];
  const float* edge_attr = (const float*)d_in[2];
  const float* Wne = (const float*)d_in[3];
  const float* bne = (const float*)d_in[4];
  const float* Wee = (const float*)d_in[5];
  const float* bee = (const float*)d_in[6];
  const float* W1 = (const float*)d_in[7];
  const float* b1 = (const float*)d_in[8];
  const float* g1 = (const float*)d_in[9];
  const float* be1 = (const float*)d_in[10];
  const float* W2 = (const float*)d_in[11];
  const float* b2 = (const float*)d_in[12];
  const float* dg = (const float*)d_in[13];
  const float* db = (const float*)d_in[14];
  const float* tpar = (const float*)d_in[15];
  const float* Wq_n = (const float*)d_in[16];
  const float* Wk_n = (const float*)d_in[17];
  const float* Wv_n = (const float*)d_in[18];
  const float* gamma_n = (const float*)d_in[19];
  const float* Wn1 = (const float*)d_in[20];
  const float* bn1 = (const float*)d_in[21];
  const float* Wn2 = (const float*)d_in[22];
  const float* bn2 = (const float*)d_in[23];
  const float* Wq_g = (const float*)d_in[24];
  const float* Wk_g = (const float*)d_in[25];
  const float* Wv_g = (const float*)d_in[26];
  const float* gamma_g = (const float*)d_in[27];
  const float* Wg1 = (const float*)d_in[28];
  const float* bg1 = (const float*)d_in[29];
  const float* Wg2 = (const float*)d_in[30];
  const float* bg2 = (const float*)d_in[31];
  float* out = (float*)d_out;

  // ---- workspace carve-out (256B-aligned regions) ----
  char* pc = (char*)d_ws;
  auto alloc = [&](size_t bytes) {
    char* r = pc;
    pc += (bytes + 255) & ~(size_t)255;
    return r;
  };
  // stacked buffers: two ti-halves at row offsets 0 and MP
  float* xbuf = (float*)alloc((size_t)2 * MP * HH * 4);       // f32 residual
  __bf16* hbuf_b = (__bf16*)alloc((size_t)2 * MP * HH * 2);   // LN'd agg input
  __bf16* t256_b = (__bf16*)alloc((size_t)2 * MP * 256 * 2);  // lin1+LN out
  float* emb = (float*)alloc((size_t)NN * 2 * HH * 4);        // [N,T,H] f32
  __bf16* aggout_b = (__bf16*)alloc((size_t)2 * MP * HH * 2); // agg out
  __bf16* nf_b = (__bf16*)emb;  // 20000*576*2=23.0MB <= emb(20.5)+aggout(10.3)
  __bf16* attnb = t256_b;       // alias: node-attn out (after last lin2)
  float* buf2 = xbuf;           // alias: graph-attn out (after last lin2)
  __bf16* wt_ne = (__bf16*)alloc((size_t)128 * 576 * 2);
  __bf16* wt1 = (__bf16*)alloc((size_t)4 * 256 * 128 * 2);
  __bf16* wt2 = (__bf16*)alloc((size_t)4 * 128 * 256 * 2);
  __bf16* wtn1 = (__bf16*)alloc((size_t)256 * 256 * 2);
  float* gp_sum = (float*)alloc(256 * 4);
  int* deg = (int*)alloc((size_t)2 * NN * 4);
  int* cursor = (int*)alloc((size_t)2 * NN * 4);
  int* rowptr = (int*)alloc((size_t)(2 * NN + 2) * 4);
  Edge* edges = (Edge*)alloc((size_t)2 * EE * 8);

  const int rows4n = (NN + 3) / 4;        // wave-per-node kernels, 1 half
  const int rows4x = (2 * NN + 3) / 4;    // wave-per-node kernels, stacked
  const int gRows2 = 2 * MP / 64;         // 628 row-blocks, stacked GEMMs

  // 0. conversions
  nf_convert_kernel<<<(NN * 576 + 255) / 256, 256, 0, stream>>>(node_feature, nf_b);
  WtDescs wd;
  wd.d[0] = {Wne, wt_ne, FF, HH, 576};
  for (int l = 0; l < 4; ++l)
    wd.d[1 + l] = {W1 + (size_t)l * HH * 256, wt1 + (size_t)l * 256 * HH, HH, 256, HH};
  for (int l = 0; l < 4; ++l)
    wd.d[5 + l] = {W2 + (size_t)l * 256 * HH, wt2 + (size_t)l * HH * 256, 256, HH, 256};
  wd.d[9] = {Wn1, wtn1, 256, 256, 256};
  wt_convert_kernel<<<dim3((128 * 576 + 255) / 256, 10), 256, 0, stream>>>(wd);

  // CSR for both ti (unified rowptr, absolute edge positions & src rows)
  hipMemsetAsync(deg, 0, 2 * NN * sizeof(int), stream);
  count2_kernel<<<(2 * EE + 255) / 256, 256, 0, stream>>>(edge_index, deg);
  scan2_kernel<<<2, 1024, 0, stream>>>(deg, rowptr, cursor);
  scatter2_kernel<<<(2 * EE + 255) / 256, 256, 0, stream>>>(edge_index, edge_attr,
                                                            cursor, edges);

  // 1. node encoder -> both stacked halves of hbuf_b
  gemm_mfma<__bf16><<<dim3(1, MP / 64), 256, 0, stream>>>(nf_b, wt_ne, bne, hbuf_b,
                                                          NN, HH, 576, MP);

  // 2. layer loop, both ti at once
  for (int l = 0; l < LL; ++l) {
    agg_kernel<<<rows4x, 256, 0, stream>>>(hbuf_b, rowptr, edges, Wee, bee, tpar, l,
                                           aggout_b);
    gemm256<0><<<gRows2, 256, 0, stream>>>(aggout_b, wt1 + (size_t)l * 256 * HH,
                                           b1 + l * 2 * HH, g1 + l * 2 * HH,
                                           be1 + l * 2 * HH, nullptr, nullptr, t256_b,
                                           2 * MP, HH);
    const __bf16* w2l = wt2 + (size_t)l * HH * 256;
    const float* b2l = b2 + l * HH;
    if (l == 0)
      gemm_lin2<0><<<gRows2, 256, 0, stream>>>(t256_b, w2l, b2l, xbuf, dg + 1 * HH,
                                               db + 1 * HH, hbuf_b);
    else if (l < LL - 1)
      gemm_lin2<1><<<gRows2, 256, 0, stream>>>(t256_b, w2l, b2l, xbuf,
                                               dg + (l + 1) * HH, db + (l + 1) * HH,
                                               hbuf_b);
    else
      gemm_lin2<2><<<gRows2, 256, 0, stream>>>(t256_b, w2l, b2l, xbuf, dg, db, emb);
  }

  // node branch: attn -> [lin1+relu+Wn2+log_softmax] fused
  attn_kernel<__bf16><<<rows4n, 256, 0, stream>>>(emb, Wq_n, Wk_n, Wv_n, gamma_n,
                                                  attnb, NN);
  gemm256<1><<<MP / 64, 256, 0, stream>>>(attnb, wtn1, bn1, nullptr, nullptr, Wn2,
                                          bn2, out, NN, 256);

  // graph branch
  attn_kernel<float><<<rows4n, 256, 0, stream>>>(emb, Wq_g, Wk_g, Wv_g, gamma_g, buf2,
                                                 NN);
  hipMemsetAsync(gp_sum, 0, 256 * sizeof(float), stream);
  pool_kernel<<<128, 256, 0, stream>>>(buf2, gp_sum, NN);
  graph_head_kernel<<<1, 256, 0, stream>>>(gp_sum, Wg1, bg1, Wg2, bg2,
                                           out + (size_t)NN * CN, 1.0f / NN);
}

// Round 6
// 507.403 us; speedup vs baseline: 3.2245x; 1.0107x over previous
//
#include <hip/hip_runtime.h>

#define NN 20000
#define TT 2
#define HH 128
#define LL 4
#define EE 320000
#define FF 514
#define CN 3
#define CG 2
#define EPS_MSG 1e-7f
#define MP 20096  // rows per ti-half, padded to multiple of 128

typedef __bf16 bf16x8 __attribute__((ext_vector_type(8)));
typedef __bf16 bf16x4 __attribute__((ext_vector_type(4)));
typedef __bf16 bf16x2 __attribute__((ext_vector_type(2)));
typedef float f32x4 __attribute__((ext_vector_type(4)));

struct __align__(8) Edge { int src; __bf16 ea0, ea1; };

// ---------------- wave helpers ----------------
__device__ inline float wave_sum(float v) {
#pragma unroll
  for (int off = 32; off; off >>= 1) v += __shfl_xor(v, off);
  return v;
}
__device__ inline float red16(float v) {  // reduce across fr = lane&15
  v += __shfl_xor(v, 1); v += __shfl_xor(v, 2);
  v += __shfl_xor(v, 4); v += __shfl_xor(v, 8);
  return v;
}

__device__ __forceinline__ void gload_lds16(const void* g, void* l) {
  __builtin_amdgcn_global_load_lds(
      (const __attribute__((address_space(1))) unsigned int*)g,
      (__attribute__((address_space(3))) unsigned int*)l, 16, 0, 0);
}

// ---------------- fused encoder GEMM + edge scatter ----------------
// blocks [0, ENCB): C[gm][gn] = A@BT + bias, dup to gm+MP (BM=64,BN=128,K=576)
// blocks [ENCB, ...): counting-sort scatter of edges (independent work).
#define ENCB (MP / 64)
__global__ __launch_bounds__(256) void enc_scatter_kernel(
    const __bf16* __restrict__ A, const __bf16* __restrict__ BT,
    const float* __restrict__ bias, __bf16* __restrict__ C,
    const int* __restrict__ edge_index, const float* __restrict__ edge_attr,
    int* __restrict__ cursor, Edge* __restrict__ edges) {
  __shared__ __bf16 As[2][64][32];
  __shared__ __bf16 Bs[2][128][32];
  const int tid = threadIdx.x;
  if (blockIdx.x >= ENCB) {
    int i = (blockIdx.x - ENCB) * 256 + tid;
    if (i >= 2 * EE) return;
    int ti = (i >= EE) ? 1 : 0;
    int e = i - ti * EE;
    const int* srcp = edge_index + (size_t)ti * 2 * EE;
    int s = srcp[e], d = srcp[EE + e];
    float2 ea = ((const float2*)edge_attr)[(size_t)ti * EE + e];
    int pos = atomicAdd(&cursor[ti * NN + d], 1);
    Edge ed;
    ed.src = s + ti * MP;
    ed.ea0 = (__bf16)ea.x; ed.ea1 = (__bf16)ea.y;
    __builtin_memcpy(&edges[pos], &ed, sizeof(Edge));
    return;
  }
  const int K = 576;
  const int lane = tid & 63, w = tid >> 6;
  const int bm = blockIdx.x * 64;
  const int wr = (w >> 1) * 32, wc = (w & 1) * 64;
  const int fr = lane & 15, fq = lane >> 4;
  const int rowA = tid >> 2, chA = (tid & 3) * 8;
  const __bf16* Ab = A + (size_t)(bm + rowA) * K + chA;
  const __bf16* Bb = BT + (size_t)rowA * K + chA;
  const __bf16* Bb2 = Bb + (size_t)64 * K;
  f32x4 acc[2][4] = {};
#define STAGE(buf, k0)                                  \
  do {                                                  \
    gload_lds16(Ab + (k0), &As[buf][rowA][chA]);        \
    gload_lds16(Bb + (k0), &Bs[buf][rowA][chA]);        \
    gload_lds16(Bb2 + (k0), &Bs[buf][rowA + 64][chA]);  \
  } while (0)
  STAGE(0, 0);
  __syncthreads();
  int cur = 0;
  for (int k0 = 0; k0 < K; k0 += 32) {
    if (k0 + 32 < K) STAGE(cur ^ 1, k0 + 32);
    bf16x8 af[2], bq[4];
#pragma unroll
    for (int m = 0; m < 2; ++m)
      af[m] = *(const bf16x8*)&As[cur][wr + m * 16 + fr][fq * 8];
#pragma unroll
    for (int n = 0; n < 4; ++n)
      bq[n] = *(const bf16x8*)&Bs[cur][wc + n * 16 + fr][fq * 8];
#pragma unroll
    for (int m = 0; m < 2; ++m)
#pragma unroll
      for (int n = 0; n < 4; ++n)
        acc[m][n] =
            __builtin_amdgcn_mfma_f32_16x16x32_bf16(af[m], bq[n], acc[m][n], 0, 0, 0);
    __syncthreads();
    cur ^= 1;
  }
#undef STAGE
#pragma unroll
  for (int m = 0; m < 2; ++m) {
#pragma unroll
    for (int n = 0; n < 4; ++n) {
#pragma unroll
      for (int j = 0; j < 4; ++j) {
        int gm = bm + wr + m * 16 + fq * 4 + j;
        int gn = wc + n * 16 + fr;
        if (gm < NN) {
          __bf16 c = (__bf16)(acc[m][n][j] + bias[gn]);
          C[(size_t)gm * 128 + gn] = c;
          C[(size_t)(gm + MP) * 128 + gn] = c;
        }
      }
    }
  }
}

// ---------------- fused 256-wide GEMM (BM=64, BN=256, full row per wave) ----
// EPI 0: LN(c; g,be) -> relu -> bf16 out [rows][256]
// EPI 1: relu(c) -> @W2h[256,3] + b2h -> log_softmax -> f32 out [M][3]
template <int EPI>
__global__ __launch_bounds__(256) void gemm256(
    const __bf16* __restrict__ A, const __bf16* __restrict__ BT,
    const float* __restrict__ bias, const float* __restrict__ g,
    const float* __restrict__ be, const float* __restrict__ W2h,
    const float* __restrict__ b2h, void* __restrict__ outp, int M, int K) {
  __shared__ __bf16 As[2][64][32];
  __shared__ __bf16 Bs[2][256][32];
  const int tid = threadIdx.x;
  const int lane = tid & 63, w = tid >> 6;
  const int bm = blockIdx.x * 64;
  const int wr = w * 16;
  const int fr = lane & 15, fq = lane >> 4;
  const int rowA = tid >> 2, chA = (tid & 3) * 8;
  const __bf16* Ab = A + (size_t)(bm + rowA) * K + chA;
  const __bf16* Bb = BT + (size_t)rowA * K + chA;
  f32x4 acc[16] = {};

#define STG(buf, k0)                                                \
  do {                                                              \
    gload_lds16(Ab + (k0), &As[buf][rowA][chA]);                    \
    _Pragma("unroll") for (int r = 0; r < 4; ++r)                   \
        gload_lds16(Bb + (size_t)(r * 64) * K + (k0),               \
                    &Bs[buf][rowA + r * 64][chA]);                  \
  } while (0)

  STG(0, 0);
  __syncthreads();
  int cur = 0;
  for (int k0 = 0; k0 < K; k0 += 32) {
    if (k0 + 32 < K) STG(cur ^ 1, k0 + 32);
    bf16x8 af = *(const bf16x8*)&As[cur][wr + fr][fq * 8];
#pragma unroll
    for (int n = 0; n < 16; ++n) {
      bf16x8 bq = *(const bf16x8*)&Bs[cur][n * 16 + fr][fq * 8];
      acc[n] = __builtin_amdgcn_mfma_f32_16x16x32_bf16(af, bq, acc[n], 0, 0, 0);
    }
    __syncthreads();
    cur ^= 1;
  }
#undef STG

  float cb[16];
#pragma unroll
  for (int n = 0; n < 16; ++n) cb[n] = bias[n * 16 + fr];

  if constexpr (EPI == 0) {
    float gv[16], bev[16];
#pragma unroll
    for (int n = 0; n < 16; ++n) {
      gv[n] = g[n * 16 + fr];
      bev[n] = be[n * 16 + fr];
    }
    __bf16* outb = (__bf16*)outp;
#pragma unroll
    for (int j = 0; j < 4; ++j) {
      float cj[16], s = 0.f, s2 = 0.f;
#pragma unroll
      for (int n = 0; n < 16; ++n) {
        float c = acc[n][j] + cb[n];
        cj[n] = c; s += c; s2 += c * c;
      }
      s = red16(s); s2 = red16(s2);
      float mu = s * (1.f / 256);
      float var = fmaxf(s2 * (1.f / 256) - mu * mu, 0.f);
      float rr = rsqrtf(var + 1e-5f);
      int gm = bm + wr + fq * 4 + j;
      __bf16* op = outb + (size_t)gm * 256;
#pragma unroll
      for (int n = 0; n < 16; ++n) {
        float y = (cj[n] - mu) * rr * gv[n] + bev[n];
        op[n * 16 + fr] = (__bf16)fmaxf(y, 0.f);
      }
    }
  } else {
    float w0[16], w1[16], w2[16];
#pragma unroll
    for (int n = 0; n < 16; ++n) {
      int col = n * 16 + fr;
      w0[n] = W2h[col * 3 + 0];
      w1[n] = W2h[col * 3 + 1];
      w2[n] = W2h[col * 3 + 2];
    }
    float* outf = (float*)outp;
#pragma unroll
    for (int j = 0; j < 4; ++j) {
      float p0 = 0.f, p1 = 0.f, p2 = 0.f;
#pragma unroll
      for (int n = 0; n < 16; ++n) {
        float h = fmaxf(acc[n][j] + cb[n], 0.f);
        p0 += h * w0[n]; p1 += h * w1[n]; p2 += h * w2[n];
      }
      p0 = red16(p0); p1 = red16(p1); p2 = red16(p2);
      int gm = bm + wr + fq * 4 + j;
      if (fr == 0 && gm < M) {
        float l0 = p0 + b2h[0], l1 = p1 + b2h[1], l2 = p2 + b2h[2];
        float m = fmaxf(l0, fmaxf(l1, l2));
        float lse = m + logf(__expf(l0 - m) + __expf(l1 - m) + __expf(l2 - m));
        outf[(size_t)gm * 3 + 0] = l0 - lse;
        outf[(size_t)gm * 3 + 1] = l1 - lse;
        outf[(size_t)gm * 3 + 2] = l2 - lse;
      }
    }
  }
}

// ---------------- lin2 GEMM + residual + fused LayerNorm+ReLU --------------
// MODE 0: write xres (no add) + LN->relu->bf16 hb      (layer 0)
// MODE 1: add xres, write xres + LN->relu->bf16 hb     (layers 1..L-2)
// MODE 2: add xres, LN->relu->f32 emb[node*256+half*128+col] (last layer)
template <int MODE>
__global__ __launch_bounds__(256) void gemm_lin2(
    const __bf16* __restrict__ A, const __bf16* __restrict__ BT,
    const float* __restrict__ bias, float* __restrict__ xres,
    const float* __restrict__ g, const float* __restrict__ be,
    void* __restrict__ lnout) {
  __shared__ __bf16 As[2][64][32];
  __shared__ __bf16 Bs[2][128][32];
  __shared__ float redS[64][2], redS2[64][2];
  const int tid = threadIdx.x;
  const int lane = tid & 63, w = tid >> 6;
  const int bm = blockIdx.x * 64;
  const int wr = (w >> 1) * 32, wc = (w & 1) * 64;
  const int fr = lane & 15, fq = lane >> 4;
  const int rowA = tid >> 2, chA = (tid & 3) * 8;
  const __bf16* Ab = A + (size_t)(bm + rowA) * 256 + chA;
  const __bf16* Bb = BT + (size_t)rowA * 256 + chA;
  const __bf16* Bb2 = Bb + (size_t)64 * 256;
  f32x4 acc[2][4] = {};

#define STAGE(buf, k0)                                  \
  do {                                                  \
    gload_lds16(Ab + (k0), &As[buf][rowA][chA]);        \
    gload_lds16(Bb + (k0), &Bs[buf][rowA][chA]);        \
    gload_lds16(Bb2 + (k0), &Bs[buf][rowA + 64][chA]);  \
  } while (0)

  STAGE(0, 0);
  __syncthreads();
  int cur = 0;
  for (int k0 = 0; k0 < 256; k0 += 32) {
    if (k0 + 32 < 256) STAGE(cur ^ 1, k0 + 32);
    bf16x8 af[2], bq[4];
#pragma unroll
    for (int m = 0; m < 2; ++m)
      af[m] = *(const bf16x8*)&As[cur][wr + m * 16 + fr][fq * 8];
#pragma unroll
    for (int n = 0; n < 4; ++n)
      bq[n] = *(const bf16x8*)&Bs[cur][wc + n * 16 + fr][fq * 8];
#pragma unroll
    for (int m = 0; m < 2; ++m)
#pragma unroll
      for (int n = 0; n < 4; ++n)
        acc[m][n] =
            __builtin_amdgcn_mfma_f32_16x16x32_bf16(af[m], bq[n], acc[m][n], 0, 0, 0);
    __syncthreads();
    cur ^= 1;
  }
#undef STAGE

  float cv[2][4][4];
#pragma unroll
  for (int m = 0; m < 2; ++m) {
    int r0 = wr + m * 16 + fq * 4;
#pragma unroll
    for (int j = 0; j < 4; ++j) {
      int gm = bm + r0 + j;
      float s = 0.f, s2 = 0.f;
#pragma unroll
      for (int n = 0; n < 4; ++n) {
        float c = acc[m][n][j] + bias[wc + n * 16 + fr];
        if (MODE != 0) c += xres[(size_t)gm * 128 + wc + n * 16 + fr];
        cv[m][n][j] = c;
        s += c; s2 += c * c;
      }
      s = red16(s); s2 = red16(s2);
      if (fr == 0) {
        redS[r0 + j][w & 1] = s;
        redS2[r0 + j][w & 1] = s2;
      }
    }
  }
  __syncthreads();
#pragma unroll
  for (int m = 0; m < 2; ++m) {
    int r0 = wr + m * 16 + fq * 4;
#pragma unroll
    for (int j = 0; j < 4; ++j) {
      int r = r0 + j;
      int gm = bm + r;
      float S = redS[r][0] + redS[r][1];
      float S2 = redS2[r][0] + redS2[r][1];
      float mu = S * (1.f / 128);
      float var = fmaxf(S2 * (1.f / 128) - mu * mu, 0.f);
      float rr = rsqrtf(var + 1e-5f);
      if constexpr (MODE < 2) {
        float* xp = xres + (size_t)gm * 128;
        __bf16* hp = (__bf16*)lnout + (size_t)gm * 128;
#pragma unroll
        for (int n = 0; n < 4; ++n) {
          int col = wc + n * 16 + fr;
          float c = cv[m][n][j];
          xp[col] = c;
          float y = (c - mu) * rr * g[col] + be[col];
          hp[col] = (__bf16)fmaxf(y, 0.f);
        }
      } else {
        int half = gm >= MP;
        int node = gm - half * MP;
        if (node < NN) {
          float* ep = (float*)lnout + (size_t)node * 256 + half * 128;
#pragma unroll
          for (int n = 0; n < 4; ++n) {
            int col = wc + n * 16 + fr;
            float y = (cv[m][n][j] - mu) * rr * g[col] + be[col];
            ep[col] = fmaxf(y, 0.f);
          }
        }
      }
    }
  }
}

// ---------------- fused prologue: nf convert | wt convert | count | zero ----
struct WtDesc { const float* src; __bf16* dst; int K, N, Kpad; };
struct WtDescs { WtDesc d[10]; };
#define NFB 45000
#define WTB 2880
#define CNTB 2500

__global__ void prep_kernel(const float* __restrict__ nf_src,
                            __bf16* __restrict__ nf_dst, WtDescs descs,
                            const int* __restrict__ edge_index,
                            int* __restrict__ deg, float* __restrict__ gp_sum) {
  int b = blockIdx.x, tid = threadIdx.x;
  if (b < NFB) {
    int idx = b * 256 + tid;
    int row = idx / 576, col = idx - row * 576;
    float v = (col < FF) ? nf_src[(size_t)row * FF + col] : 0.f;
    nf_dst[idx] = (__bf16)v;
  } else if (b < NFB + WTB) {
    int wb = b - NFB;
    WtDesc de = descs.d[wb / 288];
    int idx = (wb % 288) * 256 + tid;
    if (idx >= de.N * de.Kpad) return;
    int n = idx / de.Kpad, k = idx - n * de.Kpad;
    float v = (k < de.K) ? de.src[(size_t)k * de.N + n] : 0.f;
    de.dst[idx] = (__bf16)v;
  } else if (b < NFB + WTB + CNTB) {
    int i = (b - NFB - WTB) * 256 + tid;
    if (i >= 2 * EE) return;
    int ti = (i >= EE) ? 1 : 0;
    int e = i - ti * EE;
    int d = edge_index[(size_t)ti * 2 * EE + EE + e];
    atomicAdd(&deg[ti * NN + d], 1);
  } else {
    gp_sum[tid] = 0.f;
  }
}

// ---------------- CSR scan (block per ti) ----------------
__global__ __launch_bounds__(1024) void scan2_kernel(
    const int* __restrict__ deg_all, int* __restrict__ rowptr,
    int* __restrict__ cursor) {
  const int ti = blockIdx.x;
  const int* deg = deg_all + ti * NN;
  __shared__ int sums[1024];
  int tid = threadIdx.x;
  int chunk = (NN + 1023) / 1024;
  int begin = tid * chunk, end = min(begin + chunk, NN);
  int s = 0;
  for (int i = begin; i < end; ++i) s += deg[i];
  sums[tid] = s;
  __syncthreads();
  for (int off = 1; off < 1024; off <<= 1) {
    int v = (tid >= off) ? sums[tid - off] : 0;
    __syncthreads();
    sums[tid] += v;
    __syncthreads();
  }
  int running = ti * EE + sums[tid] - s;
  for (int i = begin; i < end; ++i) {
    rowptr[ti * NN + i] = running;
    cursor[ti * NN + i] = running;
    running += deg[i];
  }
  if (tid == 0 && ti == 1) rowptr[2 * NN] = 2 * EE;
}

// ---------------- GENConv softmax aggregation + residual -------------------
// Half-wave per edge: lanes [0,32) handle even edges, [32,64) odd edges;
// lane covers 4 channels (bf16x4). XCD-partitioned blockIdx remap: half 0
// of the stacked x on XCDs 0-3, half 1 on XCDs 4-7 (L2 working-set split).
__global__ __launch_bounds__(256) void agg_kernel(
    const __bf16* __restrict__ xin, const int* __restrict__ rowptr,
    const Edge* __restrict__ edges, const float* __restrict__ Wee,
    const float* __restrict__ bee, const float* __restrict__ tptr, int layer,
    __bf16* __restrict__ out) {
  int wave = threadIdx.x >> 6, lane = threadIdx.x & 63;
  int b = blockIdx.x;  // 10000 blocks
  int h8 = b & 7;
  int half = h8 >> 2;
  int within = (b >> 3) * 4 + (h8 & 3);   // 0..4999
  int node = within * 4 + wave;           // 0..19999
  int gnode = half * NN + node;
  int xrow = half * MP + node;
  float t = tptr[layer];
  int hh = lane >> 5, c32 = lane & 31, c0 = c32 * 4;
  float w0[4], w1[4], bv[4];
#pragma unroll
  for (int i = 0; i < 4; ++i) {
    w0[i] = Wee[c0 + i];
    w1[i] = Wee[HH + c0 + i];
    bv[i] = bee[c0 + i];
  }
  float den[4] = {}, num[4] = {};
  int e = rowptr[gnode], e1 = rowptr[gnode + 1];

#define MLP4(XV, ED)                                              \
  do {                                                            \
    float eax = (float)(ED).ea0, eay = (float)(ED).ea1;           \
    _Pragma("unroll") for (int i = 0; i < 4; ++i) {               \
      float m = (float)(XV)[i] + eax * w0[i] + eay * w1[i] + bv[i]; \
      m = fmaxf(m, 0.f) + EPS_MSG;                                \
      float ex = __expf(m * t);                                   \
      den[i] += ex; num[i] += m * ex;                             \
    }                                                             \
  } while (0)

  for (; e + 4 <= e1; e += 4) {
    Edge Ea = edges[e + hh];
    Edge Eb = edges[e + 2 + hh];
    bf16x4 xa = *(const bf16x4*)(xin + (size_t)Ea.src * HH + c0);
    bf16x4 xb = *(const bf16x4*)(xin + (size_t)Eb.src * HH + c0);
    MLP4(xa, Ea);
    MLP4(xb, Eb);
  }
  if (e + hh < e1) {
    Edge Ea = edges[e + hh];
    bf16x4 xa = *(const bf16x4*)(xin + (size_t)Ea.src * HH + c0);
    MLP4(xa, Ea);
  }
  if (e + 2 + hh < e1) {
    Edge Ea = edges[e + 2 + hh];
    bf16x4 xa = *(const bf16x4*)(xin + (size_t)Ea.src * HH + c0);
    MLP4(xa, Ea);
  }
#undef MLP4

#pragma unroll
  for (int i = 0; i < 4; ++i) {
    den[i] += __shfl_xor(den[i], 32);
    num[i] += __shfl_xor(num[i], 32);
  }
  if (hh == 0) {
    bf16x4 xr = *(const bf16x4*)(xin + (size_t)xrow * HH + c0);
    bf16x4 o;
#pragma unroll
    for (int i = 0; i < 4; ++i)
      o[i] = (__bf16)(num[i] / (den[i] + 1e-16f) + (float)xr[i]);
    *(bf16x4*)(out + (size_t)xrow * HH + c0) = o;
  }
}

// ---------------- fused channel attention (node + graph heads) -------------
__global__ __launch_bounds__(256) void attn2_kernel(
    const float* __restrict__ emb, const float* __restrict__ Wq_n,
    const float* __restrict__ Wk_n, const float* __restrict__ Wv_n,
    const float* __restrict__ gn, const float* __restrict__ Wq_g,
    const float* __restrict__ Wk_g, const float* __restrict__ Wv_g,
    const float* __restrict__ gg, __bf16* __restrict__ outn,
    float* __restrict__ outg, int nNodes) {
  int wave = threadIdx.x >> 6, lane = threadIdx.x & 63;
  int n = blockIdx.x * 4 + wave;
  if (n >= nNodes) return;
  int c0 = lane * 2;
  const float* base = emb + (size_t)n * (2 * HH);
  float2 x0 = *(const float2*)(base + c0);
  float2 x1 = *(const float2*)(base + HH + c0);

#define ATTN_BODY(Wq, Wk, Wv, GAM, O0A, O0B, O1A, O1B)                        \
  {                                                                           \
    float gamma = *(GAM);                                                     \
    float wq00 = Wq[0], wq01 = Wq[1], wq10 = Wq[2], wq11 = Wq[3];             \
    float wk00 = Wk[0], wk01 = Wk[1], wk10 = Wk[2], wk11 = Wk[3];             \
    float wv00 = Wv[0], wv01 = Wv[1], wv10 = Wv[2], wv11 = Wv[3];             \
    float q0a = wq00 * x0.x + wq01 * x1.x, q0b = wq00 * x0.y + wq01 * x1.y;   \
    float q1a = wq10 * x0.x + wq11 * x1.x, q1b = wq10 * x0.y + wq11 * x1.y;   \
    float k0a = wk00 * x0.x + wk01 * x1.x, k0b = wk00 * x0.y + wk01 * x1.y;   \
    float k1a = wk10 * x0.x + wk11 * x1.x, k1b = wk10 * x0.y + wk11 * x1.y;   \
    float v0a = wv00 * x0.x + wv01 * x1.x, v0b = wv00 * x0.y + wv01 * x1.y;   \
    float v1a = wv10 * x0.x + wv11 * x1.x, v1b = wv10 * x0.y + wv11 * x1.y;   \
    float s00 = wave_sum(q0a * k0a + q0b * k0b);                              \
    float s01 = wave_sum(q0a * k1a + q0b * k1b);                              \
    float s10 = wave_sum(q1a * k0a + q1b * k0b);                              \
    float s11 = wave_sum(q1a * k1a + q1b * k1b);                              \
    float m0 = fmaxf(s00, s01);                                               \
    float e00 = __expf(s00 - m0), e01 = __expf(s01 - m0);                     \
    float i0 = 1.f / (e00 + e01);                                             \
    float a00 = e00 * i0, a01 = e01 * i0;                                     \
    float m1 = fmaxf(s10, s11);                                               \
    float e10 = __expf(s10 - m1), e11 = __expf(s11 - m1);                     \
    float i1 = 1.f / (e10 + e11);                                             \
    float a10 = e10 * i1, a11 = e11 * i1;                                     \
    O0A = gamma * (a00 * v0a + a01 * v1a) + x0.x;                             \
    O0B = gamma * (a00 * v0b + a01 * v1b) + x0.y;                             \
    O1A = gamma * (a10 * v0a + a11 * v1a) + x1.x;                             \
    O1B = gamma * (a10 * v0b + a11 * v1b) + x1.y;                             \
  }

  float n0a, n0b, n1a, n1b;
  ATTN_BODY(Wq_n, Wk_n, Wv_n, gn, n0a, n0b, n1a, n1b);
  __bf16* opn = outn + (size_t)n * (2 * HH);
  bf16x2 t0; t0[0] = (__bf16)n0a; t0[1] = (__bf16)n0b;
  bf16x2 t1; t1[0] = (__bf16)n1a; t1[1] = (__bf16)n1b;
  *(bf16x2*)(opn + c0) = t0;
  *(bf16x2*)(opn + HH + c0) = t1;

  float g0a, g0b, g1a, g1b;
  ATTN_BODY(Wq_g, Wk_g, Wv_g, gg, g0a, g0b, g1a, g1b);
  float* opg = outg + (size_t)n * (2 * HH);
  *(float2*)(opg + c0) = make_float2(g0a, g0b);
  *(float2*)(opg + HH + c0) = make_float2(g1a, g1b);
#undef ATTN_BODY
}

// ---------------- mean pool ----------------
__global__ __launch_bounds__(256) void pool_kernel(const float* __restrict__ gbuf,
                                                   float* __restrict__ gp_sum, int nNodes) {
  int c = threadIdx.x;
  float s = 0.f;
  for (int r = blockIdx.x; r < nNodes; r += gridDim.x) s += gbuf[(size_t)r * 256 + c];
  atomicAdd(&gp_sum[c], s);
}

// ---------------- graph head (single block) ----------------
__global__ __launch_bounds__(256) void graph_head_kernel(
    const float* __restrict__ gp_sum, const float* __restrict__ Wg1,
    const float* __restrict__ bg1, const float* __restrict__ Wg2,
    const float* __restrict__ bg2, float* __restrict__ outp, float invN) {
  __shared__ float gp[256];
  __shared__ float h1[256];
  __shared__ float lg[2];
  int tid = threadIdx.x;
  gp[tid] = gp_sum[tid] * invN;
  __syncthreads();
  float acc = bg1[tid];
  for (int k = 0; k < 256; ++k) acc += gp[k] * Wg1[k * 256 + tid];
  h1[tid] = fmaxf(acc, 0.f);
  __syncthreads();
  if (tid < 2) {
    float l = bg2[tid];
    for (int c = 0; c < 256; ++c) l += h1[c] * Wg2[c * 2 + tid];
    lg[tid] = l;
  }
  __syncthreads();
  if (tid == 0) {
    float m = fmaxf(lg[0], lg[1]);
    float lse = m + logf(__expf(lg[0] - m) + __expf(lg[1] - m));
    outp[0] = lg[0] - lse;
    outp[1] = lg[1] - lse;
  }
}

// ---------------- launch ----------------
extern "C" void kernel_launch(void* const* d_in, const int* in_sizes, int n_in,
                              void* d_out, int out_size, void* d_ws, size_t ws_size,
                              hipStream_t stream) {
  (void)in_sizes; (void)n_in; (void)out_size; (void)ws_size;
  const float* node_feature = (const float*)d_in[0];
  const int* edge_index = (const int*)d_in[1];
  const float* edge_attr = (const float*)d_in[2];
  const float* Wne = (const float*)d_in[3];
  const float* bne = (const float*)d_in[4];
  const float* Wee = (const float*)d_in[5];
  const float* bee = (const float*)d_in[6];
  const float* W1 = (const float*)d_in[7];
  const float* b1 = (const float*)d_in[8];
  const float* g1 = (const float*)d_in[9];
  const float* be1 = (const float*)d_in[10];
  const float* W2 = (const float*)d_in[11];
  const float* b2 = (const float*)d_in[12];
  const float* dg = (const float*)d_in[13];
  const float* db = (const float*)d_in[14];
  const float* tpar = (const float*)d_in[15];
  const float* Wq_n = (const float*)d_in[16];
  const float* Wk_n = (const float*)d_in[17];
  const float* Wv_n = (const float*)d_in[18];
  const float* gamma_n = (const float*)d_in[19];
  const float* Wn1 = (const float*)d_in[20];
  const float* bn1 = (const float*)d_in[21];
  const float* Wn2 = (const float*)d_in[22];
  const float* bn2 = (const float*)d_in[23];
  const float* Wq_g = (const float*)d_in[24];
  const float* Wk_g = (const float*)d_in[25];
  const float* Wv_g = (const float*)d_in[26];
  const float* gamma_g = (const float*)d_in[27];
  const float* Wg1 = (const float*)d_in[28];
  const float* bg1 = (const float*)d_in[29];
  const float* Wg2 = (const float*)d_in[30];
  const float* bg2 = (const float*)d_in[31];
  float* out = (float*)d_out;

  // ---- workspace carve-out (256B-aligned regions) ----
  char* pc = (char*)d_ws;
  auto alloc = [&](size_t bytes) {
    char* r = pc;
    pc += (bytes + 255) & ~(size_t)255;
    return r;
  };
  float* xbuf = (float*)alloc((size_t)2 * MP * HH * 4);       // f32 residual
  __bf16* hbuf_b = (__bf16*)alloc((size_t)2 * MP * HH * 2);   // LN'd agg input
  __bf16* t256_b = (__bf16*)alloc((size_t)2 * MP * 256 * 2);  // lin1+LN out
  float* emb = (float*)alloc((size_t)NN * 2 * HH * 4);        // [N,T,H] f32
  __bf16* aggout_b = (__bf16*)alloc((size_t)2 * MP * HH * 2); // agg out
  __bf16* nf_b = (__bf16*)emb;  // 23.0MB <= emb(20.5)+aggout(10.3)
  __bf16* attnb = t256_b;       // alias: node-attn out (after last lin2)
  float* buf2 = xbuf;           // alias: graph-attn out (after last lin2)
  __bf16* wt_ne = (__bf16*)alloc((size_t)128 * 576 * 2);
  __bf16* wt1 = (__bf16*)alloc((size_t)4 * 256 * 128 * 2);
  __bf16* wt2 = (__bf16*)alloc((size_t)4 * 128 * 256 * 2);
  __bf16* wtn1 = (__bf16*)alloc((size_t)256 * 256 * 2);
  float* gp_sum = (float*)alloc(256 * 4);
  int* deg = (int*)alloc((size_t)2 * NN * 4);
  int* cursor = (int*)alloc((size_t)2 * NN * 4);
  int* rowptr = (int*)alloc((size_t)(2 * NN + 2) * 4);
  Edge* edges = (Edge*)alloc((size_t)2 * EE * 8);

  const int gRows2 = 2 * MP / 64;  // 628 row-blocks, stacked GEMMs

  WtDescs wd;
  wd.d[0] = {Wne, wt_ne, FF, HH, 576};
  for (int l = 0; l < 4; ++l)
    wd.d[1 + l] = {W1 + (size_t)l * HH * 256, wt1 + (size_t)l * 256 * HH, HH, 256, HH};
  for (int l = 0; l < 4; ++l)
    wd.d[5 + l] = {W2 + (size_t)l * 256 * HH, wt2 + (size_t)l * HH * 256, 256, HH, 256};
  wd.d[9] = {Wn1, wtn1, 256, 256, 256};

  // prologue: deg zero; then converts + degree count + gp_sum zero, fused
  hipMemsetAsync(deg, 0, 2 * NN * sizeof(int), stream);
  prep_kernel<<<NFB + WTB + CNTB + 1, 256, 0, stream>>>(node_feature, nf_b, wd,
                                                        edge_index, deg, gp_sum);
  scan2_kernel<<<2, 1024, 0, stream>>>(deg, rowptr, cursor);
  // encoder GEMM (dup to both halves) fused with edge scatter
  enc_scatter_kernel<<<ENCB + CNTB, 256, 0, stream>>>(
      nf_b, wt_ne, bne, hbuf_b, edge_index, edge_attr, cursor, edges);

  // layer loop, both ti at once
  for (int l = 0; l < LL; ++l) {
    agg_kernel<<<2 * NN / 4, 256, 0, stream>>>(hbuf_b, rowptr, edges, Wee, bee, tpar,
                                               l, aggout_b);
    gemm256<0><<<gRows2, 256, 0, stream>>>(aggout_b, wt1 + (size_t)l * 256 * HH,
                                           b1 + l * 2 * HH, g1 + l * 2 * HH,
                                           be1 + l * 2 * HH, nullptr, nullptr, t256_b,
                                           2 * MP, HH);
    const __bf16* w2l = wt2 + (size_t)l * HH * 256;
    const float* b2l = b2 + l * HH;
    if (l == 0)
      gemm_lin2<0><<<gRows2, 256, 0, stream>>>(t256_b, w2l, b2l, xbuf, dg + 1 * HH,
                                               db + 1 * HH, hbuf_b);
    else if (l < LL - 1)
      gemm_lin2<1><<<gRows2, 256, 0, stream>>>(t256_b, w2l, b2l, xbuf,
                                               dg + (l + 1) * HH, db + (l + 1) * HH,
                                               hbuf_b);
    else
      gemm_lin2<2><<<gRows2, 256, 0, stream>>>(t256_b, w2l, b2l, xbuf, dg, db, emb);
  }

  // fused node+graph attention (one emb read)
  attn2_kernel<<<(NN + 3) / 4, 256, 0, stream>>>(emb, Wq_n, Wk_n, Wv_n, gamma_n,
                                                 Wq_g, Wk_g, Wv_g, gamma_g, attnb,
                                                 buf2, NN);
  // node head: lin1+relu+Wn2+log_softmax fused
  gemm256<1><<<MP / 64, 256, 0, stream>>>(attnb, wtn1, bn1, nullptr, nullptr, Wn2,
                                          bn2, out, NN, 256);
  // graph head
  pool_kernel<<<128, 256, 0, stream>>>(buf2, gp_sum, NN);
  graph_head_kernel<<<1, 256, 0, stream>>>(gp_sum, Wg1, bg1, Wg2, bg2,
                                           out + (size_t)NN * CN, 1.0f / NN);
}